// Round 7
// baseline (252.789 us; speedup 1.0000x reference)
//
#include <hip/hip_runtime.h>
#include <hip/hip_bf16.h>

typedef __attribute__((ext_vector_type(8))) short short8;
typedef __attribute__((ext_vector_type(4))) short short4v;
typedef __attribute__((ext_vector_type(4))) float f32x4;

#define B_ 16
#define T_ 1024
#define C_ 512
#define NH 8
#define HD 64

__device__ __forceinline__ short f2bf(float f) {
  union { float f; unsigned u; } v;
  v.f = f;
  unsigned r = v.u + 0x7fffu + ((v.u >> 16) & 1u);
  return (short)(r >> 16);
}

__device__ __forceinline__ short2 pack_bf2(float a, float b) {
  __hip_bfloat162 t = __float22bfloat162_rn(make_float2(a, b));
  short2 r;
  __builtin_memcpy(&r, &t, 4);
  return r;
}

// bare v_exp_f32: computes 2^x. The softmax scale folds log2(e) into Q
// at gemm_qkv, so scores arrive pre-multiplied — saves one v_mul per exp.
__device__ __forceinline__ float fexp2(float x) {
  float r;
  asm("v_exp_f32 %0, %1" : "=v"(r) : "v"(x));
  return r;
}

__device__ __forceinline__ void gload_lds16(const short* g, short* l) {
  __builtin_amdgcn_global_load_lds(
      (const __attribute__((address_space(1))) void*)g,
      (__attribute__((address_space(3))) void*)l, 16, 0, 0);
}

// ---------------- stage 1: partial sums + weight transpose (merged launch) ----
// Blocks 0..1023: GroupNorm partial sums (chunk = blk&63, b = blk>>6).
// Blocks 1024..5119: fp32 -> bf16 transposed weight prep (former kernel).
// Branch is block-uniform, so the barrier inside the stats path stays legal.
__global__ __launch_bounds__(256) void stats1_trans_kernel(
    const float* __restrict__ x, float2* __restrict__ partials,
    const float* __restrict__ wq, const float* __restrict__ wk,
    const float* __restrict__ wv, const float* __restrict__ wo,
    short* __restrict__ wqkvT, short* __restrict__ woT) {
  int blk = blockIdx.x;
  int tid = threadIdx.x;
  if (blk < 1024) {
    int chunk = blk & 63;
    int b = blk >> 6;
    const float4* xb = (const float4*)(x + (size_t)b * 524288 + (size_t)chunk * 8192);
    float s = 0.f, s2 = 0.f;
#pragma unroll
    for (int i = 0; i < 8; i++) {
      float4 v = xb[tid + i * 256];
      s  += v.x + v.y + v.z + v.w;
      s2 += v.x * v.x + v.y * v.y + v.z * v.z + v.w * v.w;
    }
    __shared__ float ls[256], ls2[256];
    ls[tid] = s; ls2[tid] = s2;
    __syncthreads();
    for (int o = 128; o > 0; o >>= 1) {
      if (tid < o) { ls[tid] += ls[tid + o]; ls2[tid] += ls2[tid + o]; }
      __syncthreads();
    }
    if (tid == 0) partials[b * 64 + chunk] = make_float2(ls[0], ls2[0]);
  } else {
    int o = (blk - 1024) * 256 + tid;
    int sel = o >> 18;
    int oo = o & 262143;
    int k = oo >> 9, n = oo & 511;
    const float* w = (sel == 0) ? wq : (sel == 1) ? wk : (sel == 2) ? wv : wo;
    float val = w[oo];
    if (sel < 3) wqkvT[((size_t)(sel * 512 + n)) * 512 + k] = f2bf(val);
    else         woT[(size_t)n * 512 + k] = f2bf(val);
  }
}

// ---------------- stage 2: normalize + affine -> bf16 (stats2 fused) --------
// Each block covers 1024 contiguous floats of one sample (b = blk>>9) and
// redundantly reduces that sample's 64 partials (512B, L2-hit) in wave 0 —
// removes the former stats2 dispatch + launch gap.
__global__ __launch_bounds__(256) void norm_kernel(const float* __restrict__ x,
                                                   const float* __restrict__ gamma,
                                                   const float* __restrict__ beta,
                                                   const float2* __restrict__ partials,
                                                   short* __restrict__ xn) {
  __shared__ float sm[2];
  int tid = threadIdx.x;
  int b = blockIdx.x >> 9;
  if (tid < 64) {
    float2 p = partials[b * 64 + tid];
    float s = p.x, s2 = p.y;
#pragma unroll
    for (int off = 1; off < 64; off <<= 1) {
      s  += __shfl_xor(s,  off, 64);
      s2 += __shfl_xor(s2, off, 64);
    }
    if (tid == 0) {
      float mean = s * (1.f / 524288.f);
      float var  = s2 * (1.f / 524288.f) - mean * mean;
      sm[0] = mean;
      sm[1] = rsqrtf(var + 1e-5f);
    }
  }
  __syncthreads();
  float mean = sm[0], rstd = sm[1];
  size_t i4 = (size_t)blockIdx.x * 256 + tid;
  float4 v = ((const float4*)x)[i4];
  int c = (int)((i4 * 4) & 511);
  short4v o;
  o[0] = f2bf((v.x - mean) * rstd * gamma[c + 0] + beta[c + 0]);
  o[1] = f2bf((v.y - mean) * rstd * gamma[c + 1] + beta[c + 1]);
  o[2] = f2bf((v.z - mean) * rstd * gamma[c + 2] + beta[c + 2]);
  o[3] = f2bf((v.w - mean) * rstd * gamma[c + 3] + beta[c + 3]);
  ((short4v*)xn)[i4] = o;
}

// ---------------- stage 4: fused QKV GEMM (m97 structure) ----------------
// Q segment (seg 0) pre-scaled by 0.125*log2(e): folds softmax 1/sqrt(64)
// AND the exp->exp2 base conversion. Q,K write to the compact qkv buffer
// (1024 cols: Q|K). V segment writes DIRECTLY in the permuted vT layout.
// r7: Q/K C-write via LDS exchange -> 4x short8 coalesced stores per thread
// (was 64x scalar 2B stores; epilogue dominated at K=512 / 16 K-steps).
__global__ __launch_bounds__(256) void gemm_qkv(const short* __restrict__ A,
                                                const short* __restrict__ Bt,
                                                const float* __restrict__ bq,
                                                const float* __restrict__ bk,
                                                const float* __restrict__ bv,
                                                short* __restrict__ C,
                                                short* __restrict__ vT) {
  __shared__ __align__(16) short As[128 * 32];
  __shared__ __align__(16) short Bs[128 * 32];
  __shared__ __align__(16) short ex[64 * 136];   // epilogue exchange (17408B)
  int tid = threadIdx.x;
  int w = tid >> 6, lane = tid & 63;
  int quad = lane >> 4, l16 = lane & 15;
  int mw = (w >> 1) * 64, nw = (w & 1) * 64;
  int seg = (blockIdx.x * 128) >> 9;
  const float* bias = (seg == 0) ? bq : (seg == 1) ? bk : bv;
  float smul = (seg == 0) ? 0.18033688011112042f : 1.0f;
  const short* Atile = A + (size_t)(blockIdx.y * 128) * 512;
  const short* Btile = Bt + (size_t)(blockIdx.x * 128) * 512;
  int srow = (w << 4) + (lane >> 2);
  int scol = (lane & 3) * 8;
  f32x4 acc[4][4] = {};
  for (int k0 = 0; k0 < 512; k0 += 32) {
    __syncthreads();
    gload_lds16(&Atile[(size_t)srow * 512 + k0 + scol],        &As[w * 512]);
    gload_lds16(&Atile[(size_t)(srow + 64) * 512 + k0 + scol], &As[2048 + w * 512]);
    gload_lds16(&Btile[(size_t)srow * 512 + k0 + scol],        &Bs[w * 512]);
    gload_lds16(&Btile[(size_t)(srow + 64) * 512 + k0 + scol], &Bs[2048 + w * 512]);
    __syncthreads();
    short8 af[4], bf[4];
#pragma unroll
    for (int i = 0; i < 4; i++) af[i] = *(const short8*)(&As[(mw + i * 16 + l16) * 32 + quad * 8]);
#pragma unroll
    for (int i = 0; i < 4; i++) bf[i] = *(const short8*)(&Bs[(nw + i * 16 + l16) * 32 + quad * 8]);
#pragma unroll
    for (int mi = 0; mi < 4; mi++)
#pragma unroll
      for (int ni = 0; ni < 4; ni++)
        acc[mi][ni] = __builtin_amdgcn_mfma_f32_16x16x32_bf16(af[mi], bf[ni], acc[mi][ni], 0, 0, 0);
  }
  int n0 = blockIdx.x * 128 + nw;
  if (seg < 2) {
    // LDS-exchange epilogue: half h covers block rows h*64..h*64+63
    // (owned by waves with w>>1 == h); all 256 threads then store
    // coalesced short8 rows.
#pragma unroll
    for (int h = 0; h < 2; h++) {
      __syncthreads();
      if ((w >> 1) == h) {
#pragma unroll
        for (int mi = 0; mi < 4; mi++)
#pragma unroll
          for (int ni = 0; ni < 4; ni++) {
            int gcol = n0 + ni * 16 + l16;       // 0..1023 (Q|K)
            float bval = bias[gcol & 511];
            int lcol = nw + ni * 16 + l16;       // 0..127
#pragma unroll
            for (int r = 0; r < 4; r++)
              ex[(mi * 16 + quad * 4 + r) * 136 + lcol] =
                  f2bf((acc[mi][ni][r] + bval) * smul);
          }
      }
      __syncthreads();
      int q = tid >> 2, sg = tid & 3;
      int row = blockIdx.y * 128 + h * 64 + q;
      const short* sp = &ex[q * 136 + sg * 32];
      short8 v0 = *(const short8*)sp;
      short8 v1 = *(const short8*)(sp + 8);
      short8 v2 = *(const short8*)(sp + 16);
      short8 v3 = *(const short8*)(sp + 24);
      short* dp = C + (size_t)row * 1024 + blockIdx.x * 128 + sg * 32;
      *(short8*)dp = v0;
      *(short8*)(dp + 8) = v1;
      *(short8*)(dp + 16) = v2;
      *(short8*)(dp + 24) = v3;
    }
  } else {
    // V -> vT[(b*8+h)*64 + d][chunk*128 + slot]; slot = mi*32+quad*8+half*4+r
    int m0v = blockIdx.y * 128 + mw;
    (void)m0v;
    int b = blockIdx.y >> 3;
    int chunk = blockIdx.y & 7;
    int half = mw >> 6;                      // 0 or 1
#pragma unroll
    for (int mi = 0; mi < 4; mi++)
#pragma unroll
      for (int ni = 0; ni < 4; ni++) {
        int c = (n0 - 1024) + ni * 16 + l16; // 0..511 v-col
        int h = c >> 6, d = c & 63;
        float bval = bias[c];
        short4v pk;
#pragma unroll
        for (int r = 0; r < 4; r++) pk[r] = f2bf(acc[mi][ni][r] + bval);
        short* dst = vT + ((size_t)((b * 8 + h) * 64 + d)) * 1024
                        + chunk * 128 + mi * 32 + quad * 8 + half * 4;
        *(short4v*)dst = pk;
      }
  }
}

// ---------------- stage 6: GEMM + bias + residual (fp32 out) ----------------
// r7: MFMA operands SWAPPED (mfma(bf, af) computes C^T fragments) so each
// lane holds 4 consecutive output COLUMNS at one row -> float4 bias load,
// float4 xres load, float4 store (16 each; line-complete per wave) instead
// of 64 scalar loads + 64 scalar stores.
__global__ __launch_bounds__(256) void gemm_out(const short* __restrict__ A,
                                                const short* __restrict__ Bt,
                                                const float* __restrict__ bias,
                                                const float* __restrict__ xres,
                                                float* __restrict__ out) {
  __shared__ __align__(16) short As[128 * 32];
  __shared__ __align__(16) short Bs[128 * 32];
  int tid = threadIdx.x;
  int w = tid >> 6, lane = tid & 63;
  int quad = lane >> 4, l16 = lane & 15;
  int mw = (w >> 1) * 64, nw = (w & 1) * 64;
  const short* Atile = A + (size_t)(blockIdx.y * 128) * 512;
  const short* Btile = Bt + (size_t)(blockIdx.x * 128) * 512;
  int srow = (w << 4) + (lane >> 2);
  int scol = (lane & 3) * 8;
  f32x4 acc[4][4] = {};   // acc[mi][ni] holds C^T frag: row=l16, col=quad*4+r
  for (int k0 = 0; k0 < 512; k0 += 32) {
    __syncthreads();
    gload_lds16(&Atile[(size_t)srow * 512 + k0 + scol],        &As[w * 512]);
    gload_lds16(&Atile[(size_t)(srow + 64) * 512 + k0 + scol], &As[2048 + w * 512]);
    gload_lds16(&Btile[(size_t)srow * 512 + k0 + scol],        &Bs[w * 512]);
    gload_lds16(&Btile[(size_t)(srow + 64) * 512 + k0 + scol], &Bs[2048 + w * 512]);
    __syncthreads();
    short8 af[4], bf[4];
#pragma unroll
    for (int i = 0; i < 4; i++) af[i] = *(const short8*)(&As[(mw + i * 16 + l16) * 32 + quad * 8]);
#pragma unroll
    for (int i = 0; i < 4; i++) bf[i] = *(const short8*)(&Bs[(nw + i * 16 + l16) * 32 + quad * 8]);
#pragma unroll
    for (int mi = 0; mi < 4; mi++)
#pragma unroll
      for (int ni = 0; ni < 4; ni++)
        acc[mi][ni] = __builtin_amdgcn_mfma_f32_16x16x32_bf16(bf[ni], af[mi], acc[mi][ni], 0, 0, 0);
  }
  int m0 = blockIdx.y * 128 + mw;
  int n0 = blockIdx.x * 128 + nw;
#pragma unroll
  for (int mi = 0; mi < 4; mi++)
#pragma unroll
    for (int ni = 0; ni < 4; ni++) {
      int row = m0 + mi * 16 + l16;
      int col = n0 + ni * 16 + quad * 4;
      float4 bv = *(const float4*)(&bias[col]);
      float4 xr = *(const float4*)(&xres[(size_t)row * 512 + col]);
      float4 o;
      o.x = acc[mi][ni][0] + bv.x + xr.x;
      o.y = acc[mi][ni][1] + bv.y + xr.y;
      o.z = acc[mi][ni][2] + bv.z + xr.z;
      o.w = acc[mi][ni][3] + bv.w + xr.w;
      *(float4*)(&out[(size_t)row * 512 + col]) = o;
    }
}

// ---------------- stage 5: attention — r3-proven structure + T5 setprio -----
// (unchanged from r6: 68.6 us measured, FETCH 24.7MB, VGPR 88)
__global__ __launch_bounds__(256) void attn_kernel(const short* __restrict__ Q,
                                                   const short* __restrict__ Kmat,
                                                   const short* __restrict__ vTg,
                                                   short* __restrict__ O) {
  int tid = threadIdx.x;
  int w = tid >> 6, lane = tid & 63;
  int quad = lane >> 4, l16 = lane & 15;
  int lin = blockIdx.y * 128 + blockIdx.x;   // linear dispatch id (x fastest)
  int bh = (lin & 7) * 16 + (lin >> 7);      // XCD-chunked: xcd owns 16 bh
  int qt = (lin >> 3) & 15;                  // 16 same-bh blocks consecutive
  int b = bh >> 3, h = bh & 7;
  size_t base  = ((size_t)b * T_) * 1024 + (size_t)h * 64;
  size_t vbase = ((size_t)bh * 64) * 1024;
  size_t obase = ((size_t)b * T_) * 512 + (size_t)h * 64;
  int qrow0 = qt * 64;

  __shared__ __align__(16) char smem[32768 + 1024];
  short* KTb[2];
  KTb[0] = (short*)smem;                    // K dbuf half 0: 128 keys x 64d, swizzled
  KTb[1] = (short*)(smem + 16384);          // K dbuf half 1
  float* Lbuf = (float*)smem;               // epilogue union [q][d] pad 68 (17408B)
  float* denomL = (float*)(smem + 32768);   // outside both K buffers

  // Q as B-frags: B[k=d=quad*8+j][n=q=l16], 4 q-tiles x 2 d-halves
  short8 qf0[4], qf1[4];
#pragma unroll
  for (int g = 0; g < 4; g++) {
    const short* qp = Q + base + (size_t)(qrow0 + g * 16 + l16) * 1024 + quad * 8;
    qf0[g] = *(const short8*)qp;
    qf1[g] = *(const short8*)(qp + 32);
  }

  // K staging descriptors: lane's 16B block index bk = w*256 + n*64 + lane,
  // bank swizzle applied on the GLOBAL address side (LDS dst stays linear).
  const short* ksrc[4];
#pragma unroll
  for (int n = 0; n < 4; n++) {
    int bk = w * 256 + n * 64 + lane;
    int key = bk >> 3, jc = bk & 7;
    int dcol = jc ^ (key & 7);
    ksrc[n] = Kmat + base + (size_t)key * 1024 + dcol * 8;
  }

  // V fragment base: d-row = l16 (+f*16), key-slot = w*4+quad (vT layout)
  const short* vp0 = vTg + vbase + (size_t)l16 * 1024 + (w * 4 + quad) * 8;

  // K fragment LDS offsets (shorts), loop-invariant
  int l7 = l16 & 7;
  int kA0 = ((w * 16 + l16) * 8 + (quad ^ l7)) * 8;
  int kA1 = ((w * 16 + l16) * 8 + ((quad + 4) ^ l7)) * 8;
  int kB0 = kA0 + 4096;   // key + 64
  int kB1 = kA1 + 4096;

  f32x4 oacc[4][4] = {};   // O^T[d-tile f][q-tile g]
  float lsum[4] = {0.f, 0.f, 0.f, 0.f};

  // prologue: stage tile 0 into buffer 0
#pragma unroll
  for (int n = 0; n < 4; n++)
    gload_lds16(ksrc[n], KTb[0] + (w * 256 + n * 64) * 8);

#pragma unroll
  for (int t = 0; t < 8; t++) {
    short* KTc = KTb[t & 1];
    short* KTn = KTb[(t + 1) & 1];
    __syncthreads();   // drains vmcnt: K(t) staged; KTn's last readers done
    // V fragments for tile t: global->reg, issued first
    short8 vfr[4];
#pragma unroll
    for (int f = 0; f < 4; f++)
      vfr[f] = *(const short8*)(vp0 + (size_t)f * 16384 + t * 128);
    // stage K(t+1) into the other buffer — in flight across this whole phase
    if (t < 7) {
#pragma unroll
      for (int n = 0; n < 4; n++)
        gload_lds16(ksrc[n] + (size_t)(t + 1) * 131072, KTn + (w * 256 + n * 64) * 8);
    }
    // K fragments for tile t from LDS
    short8 ka0 = *(const short8*)(KTc + kA0);
    short8 ka1 = *(const short8*)(KTc + kA1);
    short8 kb0 = *(const short8*)(KTc + kB0);
    short8 kb1 = *(const short8*)(KTc + kB1);

#pragma unroll
    for (int g = 0; g < 4; g++) {
      f32x4 za = {}, zb = {};
      __builtin_amdgcn_s_setprio(1);
      za = __builtin_amdgcn_mfma_f32_16x16x32_bf16(ka0, qf0[g], za, 0, 0, 0);
      za = __builtin_amdgcn_mfma_f32_16x16x32_bf16(ka1, qf1[g], za, 0, 0, 0);
      zb = __builtin_amdgcn_mfma_f32_16x16x32_bf16(kb0, qf0[g], zb, 0, 0, 0);
      zb = __builtin_amdgcn_mfma_f32_16x16x32_bf16(kb1, qf1[g], zb, 0, 0, 0);
      __builtin_amdgcn_s_setprio(0);
      float pa0 = fexp2(za[0]), pa1 = fexp2(za[1]);
      float pa2 = fexp2(za[2]), pa3 = fexp2(za[3]);
      float pb0 = fexp2(zb[0]), pb1 = fexp2(zb[1]);
      float pb2 = fexp2(zb[2]), pb3 = fexp2(zb[3]);
      lsum[g] += (pa0 + pa1) + (pa2 + pa3) + ((pb0 + pb1) + (pb2 + pb3));
      short2 a01 = pack_bf2(pa0, pa1), a23 = pack_bf2(pa2, pa3);
      short2 b01 = pack_bf2(pb0, pb1), b23 = pack_bf2(pb2, pb3);
      short8 pf;
      pf[0] = a01.x; pf[1] = a01.y; pf[2] = a23.x; pf[3] = a23.y;
      pf[4] = b01.x; pf[5] = b01.y; pf[6] = b23.x; pf[7] = b23.y;
      __builtin_amdgcn_s_setprio(1);
#pragma unroll
      for (int f = 0; f < 4; f++)
        oacc[f][g] = __builtin_amdgcn_mfma_f32_16x16x32_bf16(vfr[f], pf, oacc[f][g], 0, 0, 0);
      __builtin_amdgcn_s_setprio(0);
    }
  }

  // per-lane lsum covers this wave's keys for query g*16+l16; sum over quads
#pragma unroll
  for (int g = 0; g < 4; g++) {
    lsum[g] += __shfl_xor(lsum[g], 16, 64);
    lsum[g] += __shfl_xor(lsum[g], 32, 64);
  }
  if (quad == 0) {
#pragma unroll
    for (int g = 0; g < 4; g++) denomL[w * 64 + g * 16 + l16] = lsum[g];
  }
  // sequential cross-wave accumulation of O^T into Lbuf (transposed to [q][d])
  for (int ww = 0; ww < 4; ww++) {
    __syncthreads();
    if (w == ww) {
#pragma unroll
      for (int g = 0; g < 4; g++)
#pragma unroll
        for (int f = 0; f < 4; f++) {
          float* p = &Lbuf[(g * 16 + l16) * 68 + f * 16 + quad * 4];
          if (ww == 0) *(f32x4*)p = oacc[f][g];
          else         *(f32x4*)p = *(f32x4*)p + oacc[f][g];
        }
    }
  }
  __syncthreads();

  // coalesced writeout: thread -> (q = tid/4, 16-wide d segment)
  int q = tid >> 2, seg = tid & 3;
  float dn = denomL[q] + denomL[64 + q] + denomL[128 + q] + denomL[192 + q];
  float rinv = __frcp_rn(dn);
  const float* row = &Lbuf[q * 68 + seg * 16];
  short8 o0, o1;
#pragma unroll
  for (int i = 0; i < 8; i++) o0[i] = f2bf(row[i] * rinv);
#pragma unroll
  for (int i = 0; i < 8; i++) o1[i] = f2bf(row[8 + i] * rinv);
  short* op = O + obase + (size_t)(qrow0 + q) * 512 + seg * 16;
  *(short8*)op = o0;
  *(short8*)(op + 8) = o1;
}

extern "C" void kernel_launch(void* const* d_in, const int* in_sizes, int n_in,
                              void* d_out, int out_size, void* d_ws, size_t ws_size,
                              hipStream_t stream) {
  const float* x     = (const float*)d_in[0];
  const float* gamma = (const float*)d_in[1];
  const float* beta  = (const float*)d_in[2];
  const float* wq    = (const float*)d_in[3];
  const float* bq    = (const float*)d_in[4];
  const float* wk    = (const float*)d_in[5];
  const float* bk    = (const float*)d_in[6];
  const float* wv    = (const float*)d_in[7];
  const float* bv    = (const float*)d_in[8];
  const float* wo    = (const float*)d_in[9];
  const float* bo    = (const float*)d_in[10];
  float* out = (float*)d_out;

  char* ws = (char*)d_ws;
  const size_t XN_ELEMS = (size_t)B_ * T_ * C_;
  size_t off = 0;
  off += 256;                                              // (reserved)
  float2* partials = (float2*)(ws + off); off += 16 * 64 * sizeof(float2);
  short* xn    = (short*)(ws + off); off += XN_ELEMS * 2;
  short* wqkvT = (short*)(ws + off); off += (size_t)1536 * 512 * 2;
  short* woT   = (short*)(ws + off); off += (size_t)512 * 512 * 2;
  short* qkv   = (short*)(ws + off); off += (size_t)B_ * T_ * 1024 * 2;  // Q|K compact
  short* vTb   = (short*)(ws + off); off += XN_ELEMS * 2;
  short* ao    = (short*)(ws + off); off += XN_ELEMS * 2;

  stats1_trans_kernel<<<5120, 256, 0, stream>>>(x, partials, wq, wk, wv, wo, wqkvT, woT);
  norm_kernel<<<8192, 256, 0, stream>>>(x, gamma, beta, partials, xn);

  gemm_qkv<<<dim3(12, 128), 256, 0, stream>>>(xn, wqkvT, bq, bk, bv, qkv, vTb);

  attn_kernel<<<dim3(128, 16), 256, 0, stream>>>(qkv, qkv + 512, vTb, ao);

  gemm_out<<<dim3(4, 128), 256, 0, stream>>>(ao, woT, bo, x, out);
}

// Round 8
// 234.689 us; speedup vs baseline: 1.0771x; 1.0771x over previous
//
#include <hip/hip_runtime.h>
#include <hip/hip_bf16.h>

typedef __attribute__((ext_vector_type(8))) short short8;
typedef __attribute__((ext_vector_type(4))) short short4v;
typedef __attribute__((ext_vector_type(4))) float f32x4;

#define B_ 16
#define T_ 1024
#define C_ 512
#define NH 8
#define HD 64

__device__ __forceinline__ short f2bf(float f) {
  union { float f; unsigned u; } v;
  v.f = f;
  unsigned r = v.u + 0x7fffu + ((v.u >> 16) & 1u);
  return (short)(r >> 16);
}

__device__ __forceinline__ short2 pack_bf2(float a, float b) {
  __hip_bfloat162 t = __float22bfloat162_rn(make_float2(a, b));
  short2 r;
  __builtin_memcpy(&r, &t, 4);
  return r;
}

// bare v_exp_f32: computes 2^x. The softmax scale folds log2(e) into Q
// at gemm_qkv, so scores arrive pre-multiplied — saves one v_mul per exp.
__device__ __forceinline__ float fexp2(float x) {
  float r;
  asm("v_exp_f32 %0, %1" : "=v"(r) : "v"(x));
  return r;
}

__device__ __forceinline__ void gload_lds16(const short* g, short* l) {
  __builtin_amdgcn_global_load_lds(
      (const __attribute__((address_space(1))) void*)g,
      (__attribute__((address_space(3))) void*)l, 16, 0, 0);
}

// ---------------- stage 1: partial sums + weight transpose (merged launch) ----
// Blocks 0..1023: GroupNorm partial sums (chunk = blk&63, b = blk>>6).
// Blocks 1024..5119: fp32 -> bf16 transposed weight prep (former kernel).
// Branch is block-uniform, so the barrier inside the stats path stays legal.
__global__ __launch_bounds__(256) void stats1_trans_kernel(
    const float* __restrict__ x, float2* __restrict__ partials,
    const float* __restrict__ wq, const float* __restrict__ wk,
    const float* __restrict__ wv, const float* __restrict__ wo,
    short* __restrict__ wqkvT, short* __restrict__ woT) {
  int blk = blockIdx.x;
  int tid = threadIdx.x;
  if (blk < 1024) {
    int chunk = blk & 63;
    int b = blk >> 6;
    const float4* xb = (const float4*)(x + (size_t)b * 524288 + (size_t)chunk * 8192);
    float s = 0.f, s2 = 0.f;
#pragma unroll
    for (int i = 0; i < 8; i++) {
      float4 v = xb[tid + i * 256];
      s  += v.x + v.y + v.z + v.w;
      s2 += v.x * v.x + v.y * v.y + v.z * v.z + v.w * v.w;
    }
    __shared__ float ls[256], ls2[256];
    ls[tid] = s; ls2[tid] = s2;
    __syncthreads();
    for (int o = 128; o > 0; o >>= 1) {
      if (tid < o) { ls[tid] += ls[tid + o]; ls2[tid] += ls2[tid + o]; }
      __syncthreads();
    }
    if (tid == 0) partials[b * 64 + chunk] = make_float2(ls[0], ls2[0]);
  } else {
    int o = (blk - 1024) * 256 + tid;
    int sel = o >> 18;
    int oo = o & 262143;
    int k = oo >> 9, n = oo & 511;
    const float* w = (sel == 0) ? wq : (sel == 1) ? wk : (sel == 2) ? wv : wo;
    float val = w[oo];
    if (sel < 3) wqkvT[((size_t)(sel * 512 + n)) * 512 + k] = f2bf(val);
    else         woT[(size_t)n * 512 + k] = f2bf(val);
  }
}

// ---------------- stage 2: normalize + affine -> bf16 (stats2 fused) --------
// Each block covers 1024 contiguous floats of one sample (b = blk>>9) and
// redundantly reduces that sample's 64 partials (512B, L2-hit) in wave 0 —
// removes the former stats2 dispatch + launch gap.
__global__ __launch_bounds__(256) void norm_kernel(const float* __restrict__ x,
                                                   const float* __restrict__ gamma,
                                                   const float* __restrict__ beta,
                                                   const float2* __restrict__ partials,
                                                   short* __restrict__ xn) {
  __shared__ float sm[2];
  int tid = threadIdx.x;
  int b = blockIdx.x >> 9;
  if (tid < 64) {
    float2 p = partials[b * 64 + tid];
    float s = p.x, s2 = p.y;
#pragma unroll
    for (int off = 1; off < 64; off <<= 1) {
      s  += __shfl_xor(s,  off, 64);
      s2 += __shfl_xor(s2, off, 64);
    }
    if (tid == 0) {
      float mean = s * (1.f / 524288.f);
      float var  = s2 * (1.f / 524288.f) - mean * mean;
      sm[0] = mean;
      sm[1] = rsqrtf(var + 1e-5f);
    }
  }
  __syncthreads();
  float mean = sm[0], rstd = sm[1];
  size_t i4 = (size_t)blockIdx.x * 256 + tid;
  float4 v = ((const float4*)x)[i4];
  int c = (int)((i4 * 4) & 511);
  short4v o;
  o[0] = f2bf((v.x - mean) * rstd * gamma[c + 0] + beta[c + 0]);
  o[1] = f2bf((v.y - mean) * rstd * gamma[c + 1] + beta[c + 1]);
  o[2] = f2bf((v.z - mean) * rstd * gamma[c + 2] + beta[c + 2]);
  o[3] = f2bf((v.w - mean) * rstd * gamma[c + 3] + beta[c + 3]);
  ((short4v*)xn)[i4] = o;
}

// ---------------- stage 4: fused QKV GEMM ----------------
// r8: main loop converted to BK=64 via TWO proven [128][32] sub-tiles staged
// per phase (8 gloads/wave), halving barrier-phase count 16 -> 8. Sub-tile
// layout / ds_read offsets / epilogue are byte-identical to the r6-proven
// version (r7's LDS-exchange epilogue regressed and is reverted).
// Q segment (seg 0) pre-scaled by 0.125*log2(e): folds softmax 1/sqrt(64)
// AND the exp->exp2 base conversion. Q,K write the compact qkv buffer
// (1024 cols: Q|K). V segment writes DIRECTLY in the permuted vT layout
// (slot = mi*32+quad*8+half*4+r closed within the 4-row accumulator column).
__global__ __launch_bounds__(256) void gemm_qkv(const short* __restrict__ A,
                                                const short* __restrict__ Bt,
                                                const float* __restrict__ bq,
                                                const float* __restrict__ bk,
                                                const float* __restrict__ bv,
                                                short* __restrict__ C,
                                                short* __restrict__ vT) {
  __shared__ __align__(16) short As[2][128 * 32];
  __shared__ __align__(16) short Bs[2][128 * 32];
  int tid = threadIdx.x;
  int w = tid >> 6, lane = tid & 63;
  int quad = lane >> 4, l16 = lane & 15;
  int mw = (w >> 1) * 64, nw = (w & 1) * 64;
  int seg = (blockIdx.x * 128) >> 9;
  const float* bias = (seg == 0) ? bq : (seg == 1) ? bk : bv;
  float smul = (seg == 0) ? 0.18033688011112042f : 1.0f;
  const short* Atile = A + (size_t)(blockIdx.y * 128) * 512;
  const short* Btile = Bt + (size_t)(blockIdx.x * 128) * 512;
  int srow = (w << 4) + (lane >> 2);
  int scol = (lane & 3) * 8;
  f32x4 acc[4][4] = {};
  for (int k0 = 0; k0 < 512; k0 += 64) {
    __syncthreads();
    gload_lds16(&Atile[(size_t)srow * 512 + k0 + scol],             &As[0][w * 512]);
    gload_lds16(&Atile[(size_t)(srow + 64) * 512 + k0 + scol],      &As[0][2048 + w * 512]);
    gload_lds16(&Atile[(size_t)srow * 512 + k0 + 32 + scol],        &As[1][w * 512]);
    gload_lds16(&Atile[(size_t)(srow + 64) * 512 + k0 + 32 + scol], &As[1][2048 + w * 512]);
    gload_lds16(&Btile[(size_t)srow * 512 + k0 + scol],             &Bs[0][w * 512]);
    gload_lds16(&Btile[(size_t)(srow + 64) * 512 + k0 + scol],      &Bs[0][2048 + w * 512]);
    gload_lds16(&Btile[(size_t)srow * 512 + k0 + 32 + scol],        &Bs[1][w * 512]);
    gload_lds16(&Btile[(size_t)(srow + 64) * 512 + k0 + 32 + scol], &Bs[1][2048 + w * 512]);
    __syncthreads();
    short8 af[2][4], bf[2][4];
#pragma unroll
    for (int s = 0; s < 2; s++)
#pragma unroll
      for (int i = 0; i < 4; i++) {
        af[s][i] = *(const short8*)(&As[s][(mw + i * 16 + l16) * 32 + quad * 8]);
        bf[s][i] = *(const short8*)(&Bs[s][(nw + i * 16 + l16) * 32 + quad * 8]);
      }
#pragma unroll
    for (int mi = 0; mi < 4; mi++)
#pragma unroll
      for (int ni = 0; ni < 4; ni++) {
        acc[mi][ni] = __builtin_amdgcn_mfma_f32_16x16x32_bf16(af[0][mi], bf[0][ni], acc[mi][ni], 0, 0, 0);
        acc[mi][ni] = __builtin_amdgcn_mfma_f32_16x16x32_bf16(af[1][mi], bf[1][ni], acc[mi][ni], 0, 0, 0);
      }
  }
  int m0 = blockIdx.y * 128 + mw;
  int n0 = blockIdx.x * 128 + nw;
  if (seg < 2) {
#pragma unroll
    for (int mi = 0; mi < 4; mi++)
#pragma unroll
      for (int ni = 0; ni < 4; ni++) {
        int col = n0 + ni * 16 + l16;        // 0..1023 (Q|K)
        float bval = bias[col & 511];
#pragma unroll
        for (int r = 0; r < 4; r++) {
          int row = m0 + mi * 16 + quad * 4 + r;
          C[(size_t)row * 1024 + col] = f2bf((acc[mi][ni][r] + bval) * smul);
        }
      }
  } else {
    // V -> vT[(b*8+h)*64 + d][chunk*128 + slot]; slot = mi*32+quad*8+half*4+r
    int b = blockIdx.y >> 3;
    int chunk = blockIdx.y & 7;
    int half = mw >> 6;                      // 0 or 1
#pragma unroll
    for (int mi = 0; mi < 4; mi++)
#pragma unroll
      for (int ni = 0; ni < 4; ni++) {
        int c = (n0 - 1024) + ni * 16 + l16; // 0..511 v-col
        int h = c >> 6, d = c & 63;
        float bval = bias[c];
        short4v pk;
#pragma unroll
        for (int r = 0; r < 4; r++) pk[r] = f2bf(acc[mi][ni][r] + bval);
        short* dst = vT + ((size_t)((b * 8 + h) * 64 + d)) * 1024
                        + chunk * 128 + mi * 32 + quad * 8 + half * 4;
        *(short4v*)dst = pk;
      }
  }
}

// ---------------- stage 6: GEMM + bias + residual (fp32 out) ----------------
// (reverted to the r6-proven version; r7's operand swap + float4 epilogue was
// bundled with a regressing change and is withdrawn for clean attribution)
__global__ __launch_bounds__(256) void gemm_out(const short* __restrict__ A,
                                                const short* __restrict__ Bt,
                                                const float* __restrict__ bias,
                                                const float* __restrict__ xres,
                                                float* __restrict__ out) {
  __shared__ __align__(16) short As[128 * 32];
  __shared__ __align__(16) short Bs[128 * 32];
  int tid = threadIdx.x;
  int w = tid >> 6, lane = tid & 63;
  int quad = lane >> 4, l16 = lane & 15;
  int mw = (w >> 1) * 64, nw = (w & 1) * 64;
  const short* Atile = A + (size_t)(blockIdx.y * 128) * 512;
  const short* Btile = Bt + (size_t)(blockIdx.x * 128) * 512;
  int srow = (w << 4) + (lane >> 2);
  int scol = (lane & 3) * 8;
  f32x4 acc[4][4] = {};
  for (int k0 = 0; k0 < 512; k0 += 32) {
    __syncthreads();
    gload_lds16(&Atile[(size_t)srow * 512 + k0 + scol],        &As[w * 512]);
    gload_lds16(&Atile[(size_t)(srow + 64) * 512 + k0 + scol], &As[2048 + w * 512]);
    gload_lds16(&Btile[(size_t)srow * 512 + k0 + scol],        &Bs[w * 512]);
    gload_lds16(&Btile[(size_t)(srow + 64) * 512 + k0 + scol], &Bs[2048 + w * 512]);
    __syncthreads();
    short8 af[4], bf[4];
#pragma unroll
    for (int i = 0; i < 4; i++) af[i] = *(const short8*)(&As[(mw + i * 16 + l16) * 32 + quad * 8]);
#pragma unroll
    for (int i = 0; i < 4; i++) bf[i] = *(const short8*)(&Bs[(nw + i * 16 + l16) * 32 + quad * 8]);
#pragma unroll
    for (int mi = 0; mi < 4; mi++)
#pragma unroll
      for (int ni = 0; ni < 4; ni++)
        acc[mi][ni] = __builtin_amdgcn_mfma_f32_16x16x32_bf16(af[mi], bf[ni], acc[mi][ni], 0, 0, 0);
  }
  int m0 = blockIdx.y * 128 + mw;
  int n0 = blockIdx.x * 128 + nw;
#pragma unroll
  for (int mi = 0; mi < 4; mi++)
#pragma unroll
    for (int ni = 0; ni < 4; ni++) {
      int col = n0 + ni * 16 + l16;
      float bval = bias[col];
#pragma unroll
      for (int r = 0; r < 4; r++) {
        int row = m0 + mi * 16 + quad * 4 + r;
        out[(size_t)row * 512 + col] = acc[mi][ni][r] + bval + xres[(size_t)row * 512 + col];
      }
    }
}

// ---------------- stage 5: attention — r3-proven structure + T5 setprio -----
// (unchanged from r6: 68.6 us measured, FETCH 24.7MB, VGPR 88)
__global__ __launch_bounds__(256) void attn_kernel(const short* __restrict__ Q,
                                                   const short* __restrict__ Kmat,
                                                   const short* __restrict__ vTg,
                                                   short* __restrict__ O) {
  int tid = threadIdx.x;
  int w = tid >> 6, lane = tid & 63;
  int quad = lane >> 4, l16 = lane & 15;
  int lin = blockIdx.y * 128 + blockIdx.x;   // linear dispatch id (x fastest)
  int bh = (lin & 7) * 16 + (lin >> 7);      // XCD-chunked: xcd owns 16 bh
  int qt = (lin >> 3) & 15;                  // 16 same-bh blocks consecutive
  int b = bh >> 3, h = bh & 7;
  size_t base  = ((size_t)b * T_) * 1024 + (size_t)h * 64;
  size_t vbase = ((size_t)bh * 64) * 1024;
  size_t obase = ((size_t)b * T_) * 512 + (size_t)h * 64;
  int qrow0 = qt * 64;

  __shared__ __align__(16) char smem[32768 + 1024];
  short* KTb[2];
  KTb[0] = (short*)smem;                    // K dbuf half 0: 128 keys x 64d, swizzled
  KTb[1] = (short*)(smem + 16384);          // K dbuf half 1
  float* Lbuf = (float*)smem;               // epilogue union [q][d] pad 68 (17408B)
  float* denomL = (float*)(smem + 32768);   // outside both K buffers

  // Q as B-frags: B[k=d=quad*8+j][n=q=l16], 4 q-tiles x 2 d-halves
  short8 qf0[4], qf1[4];
#pragma unroll
  for (int g = 0; g < 4; g++) {
    const short* qp = Q + base + (size_t)(qrow0 + g * 16 + l16) * 1024 + quad * 8;
    qf0[g] = *(const short8*)qp;
    qf1[g] = *(const short8*)(qp + 32);
  }

  // K staging descriptors: lane's 16B block index bk = w*256 + n*64 + lane,
  // bank swizzle applied on the GLOBAL address side (LDS dst stays linear).
  const short* ksrc[4];
#pragma unroll
  for (int n = 0; n < 4; n++) {
    int bk = w * 256 + n * 64 + lane;
    int key = bk >> 3, jc = bk & 7;
    int dcol = jc ^ (key & 7);
    ksrc[n] = Kmat + base + (size_t)key * 1024 + dcol * 8;
  }

  // V fragment base: d-row = l16 (+f*16), key-slot = w*4+quad (vT layout)
  const short* vp0 = vTg + vbase + (size_t)l16 * 1024 + (w * 4 + quad) * 8;

  // K fragment LDS offsets (shorts), loop-invariant
  int l7 = l16 & 7;
  int kA0 = ((w * 16 + l16) * 8 + (quad ^ l7)) * 8;
  int kA1 = ((w * 16 + l16) * 8 + ((quad + 4) ^ l7)) * 8;
  int kB0 = kA0 + 4096;   // key + 64
  int kB1 = kA1 + 4096;

  f32x4 oacc[4][4] = {};   // O^T[d-tile f][q-tile g]
  float lsum[4] = {0.f, 0.f, 0.f, 0.f};

  // prologue: stage tile 0 into buffer 0
#pragma unroll
  for (int n = 0; n < 4; n++)
    gload_lds16(ksrc[n], KTb[0] + (w * 256 + n * 64) * 8);

#pragma unroll
  for (int t = 0; t < 8; t++) {
    short* KTc = KTb[t & 1];
    short* KTn = KTb[(t + 1) & 1];
    __syncthreads();   // drains vmcnt: K(t) staged; KTn's last readers done
    // V fragments for tile t: global->reg, issued first
    short8 vfr[4];
#pragma unroll
    for (int f = 0; f < 4; f++)
      vfr[f] = *(const short8*)(vp0 + (size_t)f * 16384 + t * 128);
    // stage K(t+1) into the other buffer — in flight across this whole phase
    if (t < 7) {
#pragma unroll
      for (int n = 0; n < 4; n++)
        gload_lds16(ksrc[n] + (size_t)(t + 1) * 131072, KTn + (w * 256 + n * 64) * 8);
    }
    // K fragments for tile t from LDS
    short8 ka0 = *(const short8*)(KTc + kA0);
    short8 ka1 = *(const short8*)(KTc + kA1);
    short8 kb0 = *(const short8*)(KTc + kB0);
    short8 kb1 = *(const short8*)(KTc + kB1);

#pragma unroll
    for (int g = 0; g < 4; g++) {
      f32x4 za = {}, zb = {};
      __builtin_amdgcn_s_setprio(1);
      za = __builtin_amdgcn_mfma_f32_16x16x32_bf16(ka0, qf0[g], za, 0, 0, 0);
      za = __builtin_amdgcn_mfma_f32_16x16x32_bf16(ka1, qf1[g], za, 0, 0, 0);
      zb = __builtin_amdgcn_mfma_f32_16x16x32_bf16(kb0, qf0[g], zb, 0, 0, 0);
      zb = __builtin_amdgcn_mfma_f32_16x16x32_bf16(kb1, qf1[g], zb, 0, 0, 0);
      __builtin_amdgcn_s_setprio(0);
      float pa0 = fexp2(za[0]), pa1 = fexp2(za[1]);
      float pa2 = fexp2(za[2]), pa3 = fexp2(za[3]);
      float pb0 = fexp2(zb[0]), pb1 = fexp2(zb[1]);
      float pb2 = fexp2(zb[2]), pb3 = fexp2(zb[3]);
      lsum[g] += (pa0 + pa1) + (pa2 + pa3) + ((pb0 + pb1) + (pb2 + pb3));
      short2 a01 = pack_bf2(pa0, pa1), a23 = pack_bf2(pa2, pa3);
      short2 b01 = pack_bf2(pb0, pb1), b23 = pack_bf2(pb2, pb3);
      short8 pf;
      pf[0] = a01.x; pf[1] = a01.y; pf[2] = a23.x; pf[3] = a23.y;
      pf[4] = b01.x; pf[5] = b01.y; pf[6] = b23.x; pf[7] = b23.y;
      __builtin_amdgcn_s_setprio(1);
#pragma unroll
      for (int f = 0; f < 4; f++)
        oacc[f][g] = __builtin_amdgcn_mfma_f32_16x16x32_bf16(vfr[f], pf, oacc[f][g], 0, 0, 0);
      __builtin_amdgcn_s_setprio(0);
    }
  }

  // per-lane lsum covers this wave's keys for query g*16+l16; sum over quads
#pragma unroll
  for (int g = 0; g < 4; g++) {
    lsum[g] += __shfl_xor(lsum[g], 16, 64);
    lsum[g] += __shfl_xor(lsum[g], 32, 64);
  }
  if (quad == 0) {
#pragma unroll
    for (int g = 0; g < 4; g++) denomL[w * 64 + g * 16 + l16] = lsum[g];
  }
  // sequential cross-wave accumulation of O^T into Lbuf (transposed to [q][d])
  for (int ww = 0; ww < 4; ww++) {
    __syncthreads();
    if (w == ww) {
#pragma unroll
      for (int g = 0; g < 4; g++)
#pragma unroll
        for (int f = 0; f < 4; f++) {
          float* p = &Lbuf[(g * 16 + l16) * 68 + f * 16 + quad * 4];
          if (ww == 0) *(f32x4*)p = oacc[f][g];
          else         *(f32x4*)p = *(f32x4*)p + oacc[f][g];
        }
    }
  }
  __syncthreads();

  // coalesced writeout: thread -> (q = tid/4, 16-wide d segment)
  int q = tid >> 2, seg = tid & 3;
  float dn = denomL[q] + denomL[64 + q] + denomL[128 + q] + denomL[192 + q];
  float rinv = __frcp_rn(dn);
  const float* row = &Lbuf[q * 68 + seg * 16];
  short8 o0, o1;
#pragma unroll
  for (int i = 0; i < 8; i++) o0[i] = f2bf(row[i] * rinv);
#pragma unroll
  for (int i = 0; i < 8; i++) o1[i] = f2bf(row[8 + i] * rinv);
  short* op = O + obase + (size_t)(qrow0 + q) * 512 + seg * 16;
  *(short8*)op = o0;
  *(short8*)(op + 8) = o1;
}

extern "C" void kernel_launch(void* const* d_in, const int* in_sizes, int n_in,
                              void* d_out, int out_size, void* d_ws, size_t ws_size,
                              hipStream_t stream) {
  const float* x     = (const float*)d_in[0];
  const float* gamma = (const float*)d_in[1];
  const float* beta  = (const float*)d_in[2];
  const float* wq    = (const float*)d_in[3];
  const float* bq    = (const float*)d_in[4];
  const float* wk    = (const float*)d_in[5];
  const float* bk    = (const float*)d_in[6];
  const float* wv    = (const float*)d_in[7];
  const float* bv    = (const float*)d_in[8];
  const float* wo    = (const float*)d_in[9];
  const float* bo    = (const float*)d_in[10];
  float* out = (float*)d_out;

  char* ws = (char*)d_ws;
  const size_t XN_ELEMS = (size_t)B_ * T_ * C_;
  size_t off = 0;
  off += 256;                                              // (reserved)
  float2* partials = (float2*)(ws + off); off += 16 * 64 * sizeof(float2);
  short* xn    = (short*)(ws + off); off += XN_ELEMS * 2;
  short* wqkvT = (short*)(ws + off); off += (size_t)1536 * 512 * 2;
  short* woT   = (short*)(ws + off); off += (size_t)512 * 512 * 2;
  short* qkv   = (short*)(ws + off); off += (size_t)B_ * T_ * 1024 * 2;  // Q|K compact
  short* vTb   = (short*)(ws + off); off += XN_ELEMS * 2;
  short* ao    = (short*)(ws + off); off += XN_ELEMS * 2;

  stats1_trans_kernel<<<5120, 256, 0, stream>>>(x, partials, wq, wk, wv, wo, wqkvT, woT);
  norm_kernel<<<8192, 256, 0, stream>>>(x, gamma, beta, partials, xn);

  gemm_qkv<<<dim3(12, 128), 256, 0, stream>>>(xn, wqkvT, bq, bk, bv, qkv, vTb);

  attn_kernel<<<dim3(128, 16), 256, 0, stream>>>(qkv, qkv + 512, vTb, ao);

  gemm_out<<<dim3(4, 128), 256, 0, stream>>>(ao, woT, bo, x, out);
}

// Round 9
// 232.982 us; speedup vs baseline: 1.0850x; 1.0073x over previous
//
#include <hip/hip_runtime.h>
#include <hip/hip_bf16.h>

typedef __attribute__((ext_vector_type(8))) short short8;
typedef __attribute__((ext_vector_type(4))) short short4v;
typedef __attribute__((ext_vector_type(4))) float f32x4;

#define B_ 16
#define T_ 1024
#define C_ 512
#define NH 8
#define HD 64

__device__ __forceinline__ short f2bf(float f) {
  union { float f; unsigned u; } v;
  v.f = f;
  unsigned r = v.u + 0x7fffu + ((v.u >> 16) & 1u);
  return (short)(r >> 16);
}

__device__ __forceinline__ short2 pack_bf2(float a, float b) {
  __hip_bfloat162 t = __float22bfloat162_rn(make_float2(a, b));
  short2 r;
  __builtin_memcpy(&r, &t, 4);
  return r;
}

// bare v_exp_f32: computes 2^x. The softmax scale folds log2(e) into Q
// at gemm_qkv, so scores arrive pre-multiplied — saves one v_mul per exp.
__device__ __forceinline__ float fexp2(float x) {
  float r;
  asm("v_exp_f32 %0, %1" : "=v"(r) : "v"(x));
  return r;
}

__device__ __forceinline__ void gload_lds16(const short* g, short* l) {
  __builtin_amdgcn_global_load_lds(
      (const __attribute__((address_space(1))) void*)g,
      (__attribute__((address_space(3))) void*)l, 16, 0, 0);
}

// ---------------- stage 1: partial sums + weight transpose (merged launch) ----
// Blocks 0..1023: GroupNorm partial sums (chunk = blk&63, b = blk>>6).
// Blocks 1024..5119: fp32 -> bf16 transposed weight prep (former kernel).
// Branch is block-uniform, so the barrier inside the stats path stays legal.
__global__ __launch_bounds__(256) void stats1_trans_kernel(
    const float* __restrict__ x, float2* __restrict__ partials,
    const float* __restrict__ wq, const float* __restrict__ wk,
    const float* __restrict__ wv, const float* __restrict__ wo,
    short* __restrict__ wqkvT, short* __restrict__ woT) {
  int blk = blockIdx.x;
  int tid = threadIdx.x;
  if (blk < 1024) {
    int chunk = blk & 63;
    int b = blk >> 6;
    const float4* xb = (const float4*)(x + (size_t)b * 524288 + (size_t)chunk * 8192);
    float s = 0.f, s2 = 0.f;
#pragma unroll
    for (int i = 0; i < 8; i++) {
      float4 v = xb[tid + i * 256];
      s  += v.x + v.y + v.z + v.w;
      s2 += v.x * v.x + v.y * v.y + v.z * v.z + v.w * v.w;
    }
    __shared__ float ls[256], ls2[256];
    ls[tid] = s; ls2[tid] = s2;
    __syncthreads();
    for (int o = 128; o > 0; o >>= 1) {
      if (tid < o) { ls[tid] += ls[tid + o]; ls2[tid] += ls2[tid + o]; }
      __syncthreads();
    }
    if (tid == 0) partials[b * 64 + chunk] = make_float2(ls[0], ls2[0]);
  } else {
    int o = (blk - 1024) * 256 + tid;
    int sel = o >> 18;
    int oo = o & 262143;
    int k = oo >> 9, n = oo & 511;
    const float* w = (sel == 0) ? wq : (sel == 1) ? wk : (sel == 2) ? wv : wo;
    float val = w[oo];
    if (sel < 3) wqkvT[((size_t)(sel * 512 + n)) * 512 + k] = f2bf(val);
    else         woT[(size_t)n * 512 + k] = f2bf(val);
  }
}

// ---------------- stage 2: normalize + affine -> bf16 (stats2 fused) --------
// Each block covers 1024 contiguous floats of one sample (b = blk>>9) and
// redundantly reduces that sample's 64 partials (512B, L2-hit) in wave 0 —
// removes the former stats2 dispatch + launch gap.
__global__ __launch_bounds__(256) void norm_kernel(const float* __restrict__ x,
                                                   const float* __restrict__ gamma,
                                                   const float* __restrict__ beta,
                                                   const float2* __restrict__ partials,
                                                   short* __restrict__ xn) {
  __shared__ float sm[2];
  int tid = threadIdx.x;
  int b = blockIdx.x >> 9;
  if (tid < 64) {
    float2 p = partials[b * 64 + tid];
    float s = p.x, s2 = p.y;
#pragma unroll
    for (int off = 1; off < 64; off <<= 1) {
      s  += __shfl_xor(s,  off, 64);
      s2 += __shfl_xor(s2, off, 64);
    }
    if (tid == 0) {
      float mean = s * (1.f / 524288.f);
      float var  = s2 * (1.f / 524288.f) - mean * mean;
      sm[0] = mean;
      sm[1] = rsqrtf(var + 1e-5f);
    }
  }
  __syncthreads();
  float mean = sm[0], rstd = sm[1];
  size_t i4 = (size_t)blockIdx.x * 256 + tid;
  float4 v = ((const float4*)x)[i4];
  int c = (int)((i4 * 4) & 511);
  short4v o;
  o[0] = f2bf((v.x - mean) * rstd * gamma[c + 0] + beta[c + 0]);
  o[1] = f2bf((v.y - mean) * rstd * gamma[c + 1] + beta[c + 1]);
  o[2] = f2bf((v.z - mean) * rstd * gamma[c + 2] + beta[c + 2]);
  o[3] = f2bf((v.w - mean) * rstd * gamma[c + 3] + beta[c + 3]);
  ((short4v*)xn)[i4] = o;
}

// ---------------- stage 4: fused QKV GEMM (BK=64, r8-proven) ----------------
// BK=64 via TWO proven [128][32] sub-tiles staged per phase (8 gloads/wave),
// halving barrier-phase count 16 -> 8 (r8: cut ~29us off non-attn time).
// Q segment (seg 0) pre-scaled by 0.125*log2(e): folds softmax 1/sqrt(64)
// AND the exp->exp2 base conversion. Q,K write the compact qkv buffer
// (1024 cols: Q|K). V segment writes DIRECTLY in the permuted vT layout
// (slot = mi*32+quad*8+half*4+r closed within the 4-row accumulator column).
__global__ __launch_bounds__(256) void gemm_qkv(const short* __restrict__ A,
                                                const short* __restrict__ Bt,
                                                const float* __restrict__ bq,
                                                const float* __restrict__ bk,
                                                const float* __restrict__ bv,
                                                short* __restrict__ C,
                                                short* __restrict__ vT) {
  __shared__ __align__(16) short As[2][128 * 32];
  __shared__ __align__(16) short Bs[2][128 * 32];
  int tid = threadIdx.x;
  int w = tid >> 6, lane = tid & 63;
  int quad = lane >> 4, l16 = lane & 15;
  int mw = (w >> 1) * 64, nw = (w & 1) * 64;
  int seg = (blockIdx.x * 128) >> 9;
  const float* bias = (seg == 0) ? bq : (seg == 1) ? bk : bv;
  float smul = (seg == 0) ? 0.18033688011112042f : 1.0f;
  const short* Atile = A + (size_t)(blockIdx.y * 128) * 512;
  const short* Btile = Bt + (size_t)(blockIdx.x * 128) * 512;
  int srow = (w << 4) + (lane >> 2);
  int scol = (lane & 3) * 8;
  f32x4 acc[4][4] = {};
  for (int k0 = 0; k0 < 512; k0 += 64) {
    __syncthreads();
    gload_lds16(&Atile[(size_t)srow * 512 + k0 + scol],             &As[0][w * 512]);
    gload_lds16(&Atile[(size_t)(srow + 64) * 512 + k0 + scol],      &As[0][2048 + w * 512]);
    gload_lds16(&Atile[(size_t)srow * 512 + k0 + 32 + scol],        &As[1][w * 512]);
    gload_lds16(&Atile[(size_t)(srow + 64) * 512 + k0 + 32 + scol], &As[1][2048 + w * 512]);
    gload_lds16(&Btile[(size_t)srow * 512 + k0 + scol],             &Bs[0][w * 512]);
    gload_lds16(&Btile[(size_t)(srow + 64) * 512 + k0 + scol],      &Bs[0][2048 + w * 512]);
    gload_lds16(&Btile[(size_t)srow * 512 + k0 + 32 + scol],        &Bs[1][w * 512]);
    gload_lds16(&Btile[(size_t)(srow + 64) * 512 + k0 + 32 + scol], &Bs[1][2048 + w * 512]);
    __syncthreads();
    short8 af[2][4], bf[2][4];
#pragma unroll
    for (int s = 0; s < 2; s++)
#pragma unroll
      for (int i = 0; i < 4; i++) {
        af[s][i] = *(const short8*)(&As[s][(mw + i * 16 + l16) * 32 + quad * 8]);
        bf[s][i] = *(const short8*)(&Bs[s][(nw + i * 16 + l16) * 32 + quad * 8]);
      }
#pragma unroll
    for (int mi = 0; mi < 4; mi++)
#pragma unroll
      for (int ni = 0; ni < 4; ni++) {
        acc[mi][ni] = __builtin_amdgcn_mfma_f32_16x16x32_bf16(af[0][mi], bf[0][ni], acc[mi][ni], 0, 0, 0);
        acc[mi][ni] = __builtin_amdgcn_mfma_f32_16x16x32_bf16(af[1][mi], bf[1][ni], acc[mi][ni], 0, 0, 0);
      }
  }
  int m0 = blockIdx.y * 128 + mw;
  int n0 = blockIdx.x * 128 + nw;
  if (seg < 2) {
#pragma unroll
    for (int mi = 0; mi < 4; mi++)
#pragma unroll
      for (int ni = 0; ni < 4; ni++) {
        int col = n0 + ni * 16 + l16;        // 0..1023 (Q|K)
        float bval = bias[col & 511];
#pragma unroll
        for (int r = 0; r < 4; r++) {
          int row = m0 + mi * 16 + quad * 4 + r;
          C[(size_t)row * 1024 + col] = f2bf((acc[mi][ni][r] + bval) * smul);
        }
      }
  } else {
    // V -> vT[(b*8+h)*64 + d][chunk*128 + slot]; slot = mi*32+quad*8+half*4+r
    int b = blockIdx.y >> 3;
    int chunk = blockIdx.y & 7;
    int half = mw >> 6;                      // 0 or 1
#pragma unroll
    for (int mi = 0; mi < 4; mi++)
#pragma unroll
      for (int ni = 0; ni < 4; ni++) {
        int c = (n0 - 1024) + ni * 16 + l16; // 0..511 v-col
        int h = c >> 6, d = c & 63;
        float bval = bias[c];
        short4v pk;
#pragma unroll
        for (int r = 0; r < 4; r++) pk[r] = f2bf(acc[mi][ni][r] + bval);
        short* dst = vT + ((size_t)((b * 8 + h) * 64 + d)) * 1024
                        + chunk * 128 + mi * 32 + quad * 8 + half * 4;
        *(short4v*)dst = pk;
      }
  }
}

// ---------------- stage 6: GEMM + bias + residual (fp32 out) ----------------
// r9: SAME BK=64 transform as gemm_qkv (the sole change this round) —
// two byte-identical [128][32] sub-tiles per phase, K-loop 16 -> 8 phases.
// Epilogue untouched (r7 falsified the scalar-store-cost theory).
__global__ __launch_bounds__(256) void gemm_out(const short* __restrict__ A,
                                                const short* __restrict__ Bt,
                                                const float* __restrict__ bias,
                                                const float* __restrict__ xres,
                                                float* __restrict__ out) {
  __shared__ __align__(16) short As[2][128 * 32];
  __shared__ __align__(16) short Bs[2][128 * 32];
  int tid = threadIdx.x;
  int w = tid >> 6, lane = tid & 63;
  int quad = lane >> 4, l16 = lane & 15;
  int mw = (w >> 1) * 64, nw = (w & 1) * 64;
  const short* Atile = A + (size_t)(blockIdx.y * 128) * 512;
  const short* Btile = Bt + (size_t)(blockIdx.x * 128) * 512;
  int srow = (w << 4) + (lane >> 2);
  int scol = (lane & 3) * 8;
  f32x4 acc[4][4] = {};
  for (int k0 = 0; k0 < 512; k0 += 64) {
    __syncthreads();
    gload_lds16(&Atile[(size_t)srow * 512 + k0 + scol],             &As[0][w * 512]);
    gload_lds16(&Atile[(size_t)(srow + 64) * 512 + k0 + scol],      &As[0][2048 + w * 512]);
    gload_lds16(&Atile[(size_t)srow * 512 + k0 + 32 + scol],        &As[1][w * 512]);
    gload_lds16(&Atile[(size_t)(srow + 64) * 512 + k0 + 32 + scol], &As[1][2048 + w * 512]);
    gload_lds16(&Btile[(size_t)srow * 512 + k0 + scol],             &Bs[0][w * 512]);
    gload_lds16(&Btile[(size_t)(srow + 64) * 512 + k0 + scol],      &Bs[0][2048 + w * 512]);
    gload_lds16(&Btile[(size_t)srow * 512 + k0 + 32 + scol],        &Bs[1][w * 512]);
    gload_lds16(&Btile[(size_t)(srow + 64) * 512 + k0 + 32 + scol], &Bs[1][2048 + w * 512]);
    __syncthreads();
    short8 af[2][4], bf[2][4];
#pragma unroll
    for (int s = 0; s < 2; s++)
#pragma unroll
      for (int i = 0; i < 4; i++) {
        af[s][i] = *(const short8*)(&As[s][(mw + i * 16 + l16) * 32 + quad * 8]);
        bf[s][i] = *(const short8*)(&Bs[s][(nw + i * 16 + l16) * 32 + quad * 8]);
      }
#pragma unroll
    for (int mi = 0; mi < 4; mi++)
#pragma unroll
      for (int ni = 0; ni < 4; ni++) {
        acc[mi][ni] = __builtin_amdgcn_mfma_f32_16x16x32_bf16(af[0][mi], bf[0][ni], acc[mi][ni], 0, 0, 0);
        acc[mi][ni] = __builtin_amdgcn_mfma_f32_16x16x32_bf16(af[1][mi], bf[1][ni], acc[mi][ni], 0, 0, 0);
      }
  }
  int m0 = blockIdx.y * 128 + mw;
  int n0 = blockIdx.x * 128 + nw;
#pragma unroll
  for (int mi = 0; mi < 4; mi++)
#pragma unroll
    for (int ni = 0; ni < 4; ni++) {
      int col = n0 + ni * 16 + l16;
      float bval = bias[col];
#pragma unroll
      for (int r = 0; r < 4; r++) {
        int row = m0 + mi * 16 + quad * 4 + r;
        out[(size_t)row * 512 + col] = acc[mi][ni][r] + bval + xres[(size_t)row * 512 + col];
      }
    }
}

// ---------------- stage 5: attention — r3-proven structure + T5 setprio -----
// (unchanged since r6. r8 measured it at 90us vs r6's 68.6 with IDENTICAL
// counters scaled by dur — uniform ~24% effective-clock drop, i.e. run-state
// (power/clock), not code. This round's attn dur is the diagnostic probe.)
__global__ __launch_bounds__(256) void attn_kernel(const short* __restrict__ Q,
                                                   const short* __restrict__ Kmat,
                                                   const short* __restrict__ vTg,
                                                   short* __restrict__ O) {
  int tid = threadIdx.x;
  int w = tid >> 6, lane = tid & 63;
  int quad = lane >> 4, l16 = lane & 15;
  int lin = blockIdx.y * 128 + blockIdx.x;   // linear dispatch id (x fastest)
  int bh = (lin & 7) * 16 + (lin >> 7);      // XCD-chunked: xcd owns 16 bh
  int qt = (lin >> 3) & 15;                  // 16 same-bh blocks consecutive
  int b = bh >> 3, h = bh & 7;
  size_t base  = ((size_t)b * T_) * 1024 + (size_t)h * 64;
  size_t vbase = ((size_t)bh * 64) * 1024;
  size_t obase = ((size_t)b * T_) * 512 + (size_t)h * 64;
  int qrow0 = qt * 64;

  __shared__ __align__(16) char smem[32768 + 1024];
  short* KTb[2];
  KTb[0] = (short*)smem;                    // K dbuf half 0: 128 keys x 64d, swizzled
  KTb[1] = (short*)(smem + 16384);          // K dbuf half 1
  float* Lbuf = (float*)smem;               // epilogue union [q][d] pad 68 (17408B)
  float* denomL = (float*)(smem + 32768);   // outside both K buffers

  // Q as B-frags: B[k=d=quad*8+j][n=q=l16], 4 q-tiles x 2 d-halves
  short8 qf0[4], qf1[4];
#pragma unroll
  for (int g = 0; g < 4; g++) {
    const short* qp = Q + base + (size_t)(qrow0 + g * 16 + l16) * 1024 + quad * 8;
    qf0[g] = *(const short8*)qp;
    qf1[g] = *(const short8*)(qp + 32);
  }

  // K staging descriptors: lane's 16B block index bk = w*256 + n*64 + lane,
  // bank swizzle applied on the GLOBAL address side (LDS dst stays linear).
  const short* ksrc[4];
#pragma unroll
  for (int n = 0; n < 4; n++) {
    int bk = w * 256 + n * 64 + lane;
    int key = bk >> 3, jc = bk & 7;
    int dcol = jc ^ (key & 7);
    ksrc[n] = Kmat + base + (size_t)key * 1024 + dcol * 8;
  }

  // V fragment base: d-row = l16 (+f*16), key-slot = w*4+quad (vT layout)
  const short* vp0 = vTg + vbase + (size_t)l16 * 1024 + (w * 4 + quad) * 8;

  // K fragment LDS offsets (shorts), loop-invariant
  int l7 = l16 & 7;
  int kA0 = ((w * 16 + l16) * 8 + (quad ^ l7)) * 8;
  int kA1 = ((w * 16 + l16) * 8 + ((quad + 4) ^ l7)) * 8;
  int kB0 = kA0 + 4096;   // key + 64
  int kB1 = kA1 + 4096;

  f32x4 oacc[4][4] = {};   // O^T[d-tile f][q-tile g]
  float lsum[4] = {0.f, 0.f, 0.f, 0.f};

  // prologue: stage tile 0 into buffer 0
#pragma unroll
  for (int n = 0; n < 4; n++)
    gload_lds16(ksrc[n], KTb[0] + (w * 256 + n * 64) * 8);

#pragma unroll
  for (int t = 0; t < 8; t++) {
    short* KTc = KTb[t & 1];
    short* KTn = KTb[(t + 1) & 1];
    __syncthreads();   // drains vmcnt: K(t) staged; KTn's last readers done
    // V fragments for tile t: global->reg, issued first
    short8 vfr[4];
#pragma unroll
    for (int f = 0; f < 4; f++)
      vfr[f] = *(const short8*)(vp0 + (size_t)f * 16384 + t * 128);
    // stage K(t+1) into the other buffer — in flight across this whole phase
    if (t < 7) {
#pragma unroll
      for (int n = 0; n < 4; n++)
        gload_lds16(ksrc[n] + (size_t)(t + 1) * 131072, KTn + (w * 256 + n * 64) * 8);
    }
    // K fragments for tile t from LDS
    short8 ka0 = *(const short8*)(KTc + kA0);
    short8 ka1 = *(const short8*)(KTc + kA1);
    short8 kb0 = *(const short8*)(KTc + kB0);
    short8 kb1 = *(const short8*)(KTc + kB1);

#pragma unroll
    for (int g = 0; g < 4; g++) {
      f32x4 za = {}, zb = {};
      __builtin_amdgcn_s_setprio(1);
      za = __builtin_amdgcn_mfma_f32_16x16x32_bf16(ka0, qf0[g], za, 0, 0, 0);
      za = __builtin_amdgcn_mfma_f32_16x16x32_bf16(ka1, qf1[g], za, 0, 0, 0);
      zb = __builtin_amdgcn_mfma_f32_16x16x32_bf16(kb0, qf0[g], zb, 0, 0, 0);
      zb = __builtin_amdgcn_mfma_f32_16x16x32_bf16(kb1, qf1[g], zb, 0, 0, 0);
      __builtin_amdgcn_s_setprio(0);
      float pa0 = fexp2(za[0]), pa1 = fexp2(za[1]);
      float pa2 = fexp2(za[2]), pa3 = fexp2(za[3]);
      float pb0 = fexp2(zb[0]), pb1 = fexp2(zb[1]);
      float pb2 = fexp2(zb[2]), pb3 = fexp2(zb[3]);
      lsum[g] += (pa0 + pa1) + (pa2 + pa3) + ((pb0 + pb1) + (pb2 + pb3));
      short2 a01 = pack_bf2(pa0, pa1), a23 = pack_bf2(pa2, pa3);
      short2 b01 = pack_bf2(pb0, pb1), b23 = pack_bf2(pb2, pb3);
      short8 pf;
      pf[0] = a01.x; pf[1] = a01.y; pf[2] = a23.x; pf[3] = a23.y;
      pf[4] = b01.x; pf[5] = b01.y; pf[6] = b23.x; pf[7] = b23.y;
      __builtin_amdgcn_s_setprio(1);
#pragma unroll
      for (int f = 0; f < 4; f++)
        oacc[f][g] = __builtin_amdgcn_mfma_f32_16x16x32_bf16(vfr[f], pf, oacc[f][g], 0, 0, 0);
      __builtin_amdgcn_s_setprio(0);
    }
  }

  // per-lane lsum covers this wave's keys for query g*16+l16; sum over quads
#pragma unroll
  for (int g = 0; g < 4; g++) {
    lsum[g] += __shfl_xor(lsum[g], 16, 64);
    lsum[g] += __shfl_xor(lsum[g], 32, 64);
  }
  if (quad == 0) {
#pragma unroll
    for (int g = 0; g < 4; g++) denomL[w * 64 + g * 16 + l16] = lsum[g];
  }
  // sequential cross-wave accumulation of O^T into Lbuf (transposed to [q][d])
  for (int ww = 0; ww < 4; ww++) {
    __syncthreads();
    if (w == ww) {
#pragma unroll
      for (int g = 0; g < 4; g++)
#pragma unroll
        for (int f = 0; f < 4; f++) {
          float* p = &Lbuf[(g * 16 + l16) * 68 + f * 16 + quad * 4];
          if (ww == 0) *(f32x4*)p = oacc[f][g];
          else         *(f32x4*)p = *(f32x4*)p + oacc[f][g];
        }
    }
  }
  __syncthreads();

  // coalesced writeout: thread -> (q = tid/4, 16-wide d segment)
  int q = tid >> 2, seg = tid & 3;
  float dn = denomL[q] + denomL[64 + q] + denomL[128 + q] + denomL[192 + q];
  float rinv = __frcp_rn(dn);
  const float* row = &Lbuf[q * 68 + seg * 16];
  short8 o0, o1;
#pragma unroll
  for (int i = 0; i < 8; i++) o0[i] = f2bf(row[i] * rinv);
#pragma unroll
  for (int i = 0; i < 8; i++) o1[i] = f2bf(row[8 + i] * rinv);
  short* op = O + obase + (size_t)(qrow0 + q) * 512 + seg * 16;
  *(short8*)op = o0;
  *(short8*)(op + 8) = o1;
}

extern "C" void kernel_launch(void* const* d_in, const int* in_sizes, int n_in,
                              void* d_out, int out_size, void* d_ws, size_t ws_size,
                              hipStream_t stream) {
  const float* x     = (const float*)d_in[0];
  const float* gamma = (const float*)d_in[1];
  const float* beta  = (const float*)d_in[2];
  const float* wq    = (const float*)d_in[3];
  const float* bq    = (const float*)d_in[4];
  const float* wk    = (const float*)d_in[5];
  const float* bk    = (const float*)d_in[6];
  const float* wv    = (const float*)d_in[7];
  const float* bv    = (const float*)d_in[8];
  const float* wo    = (const float*)d_in[9];
  const float* bo    = (const float*)d_in[10];
  float* out = (float*)d_out;

  char* ws = (char*)d_ws;
  const size_t XN_ELEMS = (size_t)B_ * T_ * C_;
  size_t off = 0;
  off += 256;                                              // (reserved)
  float2* partials = (float2*)(ws + off); off += 16 * 64 * sizeof(float2);
  short* xn    = (short*)(ws + off); off += XN_ELEMS * 2;
  short* wqkvT = (short*)(ws + off); off += (size_t)1536 * 512 * 2;
  short* woT   = (short*)(ws + off); off += (size_t)512 * 512 * 2;
  short* qkv   = (short*)(ws + off); off += (size_t)B_ * T_ * 1024 * 2;  // Q|K compact
  short* vTb   = (short*)(ws + off); off += XN_ELEMS * 2;
  short* ao    = (short*)(ws + off); off += XN_ELEMS * 2;

  stats1_trans_kernel<<<5120, 256, 0, stream>>>(x, partials, wq, wk, wv, wo, wqkvT, woT);
  norm_kernel<<<8192, 256, 0, stream>>>(x, gamma, beta, partials, xn);

  gemm_qkv<<<dim3(12, 128), 256, 0, stream>>>(xn, wqkvT, bq, bk, bv, qkv, vTb);

  attn_kernel<<<dim3(128, 16), 256, 0, stream>>>(qkv, qkv + 512, vTb, ao);

  gemm_out<<<dim3(4, 128), 256, 0, stream>>>(ao, woT, bo, x, out);
}

// Round 10
// 230.880 us; speedup vs baseline: 1.0949x; 1.0091x over previous
//
#include <hip/hip_runtime.h>
#include <hip/hip_bf16.h>

typedef __attribute__((ext_vector_type(8))) short short8;
typedef __attribute__((ext_vector_type(4))) short short4v;
typedef __attribute__((ext_vector_type(4))) float f32x4;

#define B_ 16
#define T_ 1024
#define C_ 512
#define NH 8
#define HD 64

__device__ __forceinline__ short f2bf(float f) {
  union { float f; unsigned u; } v;
  v.f = f;
  unsigned r = v.u + 0x7fffu + ((v.u >> 16) & 1u);
  return (short)(r >> 16);
}

__device__ __forceinline__ short2 pack_bf2(float a, float b) {
  __hip_bfloat162 t = __float22bfloat162_rn(make_float2(a, b));
  short2 r;
  __builtin_memcpy(&r, &t, 4);
  return r;
}

// bare v_exp_f32: computes 2^x. The softmax scale folds log2(e) into Q
// at gemm_qkv, so scores arrive pre-multiplied — saves one v_mul per exp.
__device__ __forceinline__ float fexp2(float x) {
  float r;
  asm("v_exp_f32 %0, %1" : "=v"(r) : "v"(x));
  return r;
}

__device__ __forceinline__ void gload_lds16(const short* g, short* l) {
  __builtin_amdgcn_global_load_lds(
      (const __attribute__((address_space(1))) void*)g,
      (__attribute__((address_space(3))) void*)l, 16, 0, 0);
}

// ---------------- stage 1: partial sums + weight transpose (merged launch) ----
// Blocks 0..1023: GroupNorm partial sums (chunk = blk&63, b = blk>>6).
// Blocks 1024..5119: fp32 -> bf16 transposed weight prep (former kernel).
// Branch is block-uniform, so the barrier inside the stats path stays legal.
__global__ __launch_bounds__(256) void stats1_trans_kernel(
    const float* __restrict__ x, float2* __restrict__ partials,
    const float* __restrict__ wq, const float* __restrict__ wk,
    const float* __restrict__ wv, const float* __restrict__ wo,
    short* __restrict__ wqkvT, short* __restrict__ woT) {
  int blk = blockIdx.x;
  int tid = threadIdx.x;
  if (blk < 1024) {
    int chunk = blk & 63;
    int b = blk >> 6;
    const float4* xb = (const float4*)(x + (size_t)b * 524288 + (size_t)chunk * 8192);
    float s = 0.f, s2 = 0.f;
#pragma unroll
    for (int i = 0; i < 8; i++) {
      float4 v = xb[tid + i * 256];
      s  += v.x + v.y + v.z + v.w;
      s2 += v.x * v.x + v.y * v.y + v.z * v.z + v.w * v.w;
    }
    __shared__ float ls[256], ls2[256];
    ls[tid] = s; ls2[tid] = s2;
    __syncthreads();
    for (int o = 128; o > 0; o >>= 1) {
      if (tid < o) { ls[tid] += ls[tid + o]; ls2[tid] += ls2[tid + o]; }
      __syncthreads();
    }
    if (tid == 0) partials[b * 64 + chunk] = make_float2(ls[0], ls2[0]);
  } else {
    int o = (blk - 1024) * 256 + tid;
    int sel = o >> 18;
    int oo = o & 262143;
    int k = oo >> 9, n = oo & 511;
    const float* w = (sel == 0) ? wq : (sel == 1) ? wk : (sel == 2) ? wv : wo;
    float val = w[oo];
    if (sel < 3) wqkvT[((size_t)(sel * 512 + n)) * 512 + k] = f2bf(val);
    else         woT[(size_t)n * 512 + k] = f2bf(val);
  }
}

// ---------------- stage 2: normalize + affine -> bf16 (stats2 fused) --------
// Each block covers 1024 contiguous floats of one sample (b = blk>>9) and
// redundantly reduces that sample's 64 partials (512B, L2-hit) in wave 0 —
// removes the former stats2 dispatch + launch gap.
__global__ __launch_bounds__(256) void norm_kernel(const float* __restrict__ x,
                                                   const float* __restrict__ gamma,
                                                   const float* __restrict__ beta,
                                                   const float2* __restrict__ partials,
                                                   short* __restrict__ xn) {
  __shared__ float sm[2];
  int tid = threadIdx.x;
  int b = blockIdx.x >> 9;
  if (tid < 64) {
    float2 p = partials[b * 64 + tid];
    float s = p.x, s2 = p.y;
#pragma unroll
    for (int off = 1; off < 64; off <<= 1) {
      s  += __shfl_xor(s,  off, 64);
      s2 += __shfl_xor(s2, off, 64);
    }
    if (tid == 0) {
      float mean = s * (1.f / 524288.f);
      float var  = s2 * (1.f / 524288.f) - mean * mean;
      sm[0] = mean;
      sm[1] = rsqrtf(var + 1e-5f);
    }
  }
  __syncthreads();
  float mean = sm[0], rstd = sm[1];
  size_t i4 = (size_t)blockIdx.x * 256 + tid;
  float4 v = ((const float4*)x)[i4];
  int c = (int)((i4 * 4) & 511);
  short4v o;
  o[0] = f2bf((v.x - mean) * rstd * gamma[c + 0] + beta[c + 0]);
  o[1] = f2bf((v.y - mean) * rstd * gamma[c + 1] + beta[c + 1]);
  o[2] = f2bf((v.z - mean) * rstd * gamma[c + 2] + beta[c + 2]);
  o[3] = f2bf((v.w - mean) * rstd * gamma[c + 3] + beta[c + 3]);
  ((short4v*)xn)[i4] = o;
}

// ---------------- stage 4: fused QKV GEMM (BK=64 + XCD swizzle) ----------------
// r10: bijective XCD-chunked block swizzle. Default x-fastest dispatch put the
// 12 consecutive blocks sharing one 128KB A-tile on 8 DIFFERENT XCDs (A-tile
// pulled into ~8 L2s from L3; staging latency exposed by the 2-barrier phase).
// Now lin=96a+t -> my=(t%8)+8a, mx=t/8: XCD lin%8 owns M-rows === c (mod 8)
// and runs all 12 N-blocks of each A-tile consecutively -> A staged from its
// own L2. Same r3-proven mechanism as attn's swizzle (-5us, FETCH 75->25MB).
// BK=64 via TWO [128][32] sub-tiles per phase (r8-proven, 8 phases).
// Q segment pre-scaled by 0.125*log2(e). Q,K -> compact qkv (1024 cols);
// V -> permuted vT layout directly.
__global__ __launch_bounds__(256) void gemm_qkv(const short* __restrict__ A,
                                                const short* __restrict__ Bt,
                                                const float* __restrict__ bq,
                                                const float* __restrict__ bk,
                                                const float* __restrict__ bv,
                                                short* __restrict__ C,
                                                short* __restrict__ vT) {
  __shared__ __align__(16) short As[2][128 * 32];
  __shared__ __align__(16) short Bs[2][128 * 32];
  int tid = threadIdx.x;
  int w = tid >> 6, lane = tid & 63;
  int quad = lane >> 4, l16 = lane & 15;
  int mw = (w >> 1) * 64, nw = (w & 1) * 64;
  int lin = blockIdx.y * 12 + blockIdx.x;   // linear dispatch id (x fastest)
  int my = (lin & 7) + ((lin / 96) << 3);   // M-tile 0..127 (XCD-chunked)
  int mx = (lin >> 3) % 12;                 // N-tile 0..11
  int seg = (mx * 128) >> 9;
  const float* bias = (seg == 0) ? bq : (seg == 1) ? bk : bv;
  float smul = (seg == 0) ? 0.18033688011112042f : 1.0f;
  const short* Atile = A + (size_t)(my * 128) * 512;
  const short* Btile = Bt + (size_t)(mx * 128) * 512;
  int srow = (w << 4) + (lane >> 2);
  int scol = (lane & 3) * 8;
  f32x4 acc[4][4] = {};
  for (int k0 = 0; k0 < 512; k0 += 64) {
    __syncthreads();
    gload_lds16(&Atile[(size_t)srow * 512 + k0 + scol],             &As[0][w * 512]);
    gload_lds16(&Atile[(size_t)(srow + 64) * 512 + k0 + scol],      &As[0][2048 + w * 512]);
    gload_lds16(&Atile[(size_t)srow * 512 + k0 + 32 + scol],        &As[1][w * 512]);
    gload_lds16(&Atile[(size_t)(srow + 64) * 512 + k0 + 32 + scol], &As[1][2048 + w * 512]);
    gload_lds16(&Btile[(size_t)srow * 512 + k0 + scol],             &Bs[0][w * 512]);
    gload_lds16(&Btile[(size_t)(srow + 64) * 512 + k0 + scol],      &Bs[0][2048 + w * 512]);
    gload_lds16(&Btile[(size_t)srow * 512 + k0 + 32 + scol],        &Bs[1][w * 512]);
    gload_lds16(&Btile[(size_t)(srow + 64) * 512 + k0 + 32 + scol], &Bs[1][2048 + w * 512]);
    __syncthreads();
    short8 af[2][4], bf[2][4];
#pragma unroll
    for (int s = 0; s < 2; s++)
#pragma unroll
      for (int i = 0; i < 4; i++) {
        af[s][i] = *(const short8*)(&As[s][(mw + i * 16 + l16) * 32 + quad * 8]);
        bf[s][i] = *(const short8*)(&Bs[s][(nw + i * 16 + l16) * 32 + quad * 8]);
      }
#pragma unroll
    for (int mi = 0; mi < 4; mi++)
#pragma unroll
      for (int ni = 0; ni < 4; ni++) {
        acc[mi][ni] = __builtin_amdgcn_mfma_f32_16x16x32_bf16(af[0][mi], bf[0][ni], acc[mi][ni], 0, 0, 0);
        acc[mi][ni] = __builtin_amdgcn_mfma_f32_16x16x32_bf16(af[1][mi], bf[1][ni], acc[mi][ni], 0, 0, 0);
      }
  }
  int m0 = my * 128 + mw;
  int n0 = mx * 128 + nw;
  if (seg < 2) {
#pragma unroll
    for (int mi = 0; mi < 4; mi++)
#pragma unroll
      for (int ni = 0; ni < 4; ni++) {
        int col = n0 + ni * 16 + l16;        // 0..1023 (Q|K)
        float bval = bias[col & 511];
#pragma unroll
        for (int r = 0; r < 4; r++) {
          int row = m0 + mi * 16 + quad * 4 + r;
          C[(size_t)row * 1024 + col] = f2bf((acc[mi][ni][r] + bval) * smul);
        }
      }
  } else {
    // V -> vT[(b*8+h)*64 + d][chunk*128 + slot]; slot = mi*32+quad*8+half*4+r
    int b = my >> 3;
    int chunk = my & 7;
    int half = mw >> 6;                      // 0 or 1
#pragma unroll
    for (int mi = 0; mi < 4; mi++)
#pragma unroll
      for (int ni = 0; ni < 4; ni++) {
        int c = (n0 - 1024) + ni * 16 + l16; // 0..511 v-col
        int h = c >> 6, d = c & 63;
        float bval = bias[c];
        short4v pk;
#pragma unroll
        for (int r = 0; r < 4; r++) pk[r] = f2bf(acc[mi][ni][r] + bval);
        short* dst = vT + ((size_t)((b * 8 + h) * 64 + d)) * 1024
                        + chunk * 128 + mi * 32 + quad * 8 + half * 4;
        *(short4v*)dst = pk;
      }
  }
}

// ---------------- stage 6: GEMM + bias + residual (fp32 out) ----------------
// r10: same XCD-chunked swizzle as gemm_qkv (4 N-blocks share each A-tile:
// lin=32a+t -> my=(t%8)+8a, mx=t/8). BK=64 (r9-proven). Epilogue untouched.
__global__ __launch_bounds__(256) void gemm_out(const short* __restrict__ A,
                                                const short* __restrict__ Bt,
                                                const float* __restrict__ bias,
                                                const float* __restrict__ xres,
                                                float* __restrict__ out) {
  __shared__ __align__(16) short As[2][128 * 32];
  __shared__ __align__(16) short Bs[2][128 * 32];
  int tid = threadIdx.x;
  int w = tid >> 6, lane = tid & 63;
  int quad = lane >> 4, l16 = lane & 15;
  int mw = (w >> 1) * 64, nw = (w & 1) * 64;
  int lin = blockIdx.y * 4 + blockIdx.x;    // linear dispatch id (x fastest)
  int my = (lin & 7) + ((lin / 32) << 3);   // M-tile 0..127 (XCD-chunked)
  int mx = (lin >> 3) & 3;                  // N-tile 0..3
  const short* Atile = A + (size_t)(my * 128) * 512;
  const short* Btile = Bt + (size_t)(mx * 128) * 512;
  int srow = (w << 4) + (lane >> 2);
  int scol = (lane & 3) * 8;
  f32x4 acc[4][4] = {};
  for (int k0 = 0; k0 < 512; k0 += 64) {
    __syncthreads();
    gload_lds16(&Atile[(size_t)srow * 512 + k0 + scol],             &As[0][w * 512]);
    gload_lds16(&Atile[(size_t)(srow + 64) * 512 + k0 + scol],      &As[0][2048 + w * 512]);
    gload_lds16(&Atile[(size_t)srow * 512 + k0 + 32 + scol],        &As[1][w * 512]);
    gload_lds16(&Atile[(size_t)(srow + 64) * 512 + k0 + 32 + scol], &As[1][2048 + w * 512]);
    gload_lds16(&Btile[(size_t)srow * 512 + k0 + scol],             &Bs[0][w * 512]);
    gload_lds16(&Btile[(size_t)(srow + 64) * 512 + k0 + scol],      &Bs[0][2048 + w * 512]);
    gload_lds16(&Btile[(size_t)srow * 512 + k0 + 32 + scol],        &Bs[1][w * 512]);
    gload_lds16(&Btile[(size_t)(srow + 64) * 512 + k0 + 32 + scol], &Bs[1][2048 + w * 512]);
    __syncthreads();
    short8 af[2][4], bf[2][4];
#pragma unroll
    for (int s = 0; s < 2; s++)
#pragma unroll
      for (int i = 0; i < 4; i++) {
        af[s][i] = *(const short8*)(&As[s][(mw + i * 16 + l16) * 32 + quad * 8]);
        bf[s][i] = *(const short8*)(&Bs[s][(nw + i * 16 + l16) * 32 + quad * 8]);
      }
#pragma unroll
    for (int mi = 0; mi < 4; mi++)
#pragma unroll
      for (int ni = 0; ni < 4; ni++) {
        acc[mi][ni] = __builtin_amdgcn_mfma_f32_16x16x32_bf16(af[0][mi], bf[0][ni], acc[mi][ni], 0, 0, 0);
        acc[mi][ni] = __builtin_amdgcn_mfma_f32_16x16x32_bf16(af[1][mi], bf[1][ni], acc[mi][ni], 0, 0, 0);
      }
  }
  int m0 = my * 128 + mw;
  int n0 = mx * 128 + nw;
#pragma unroll
  for (int mi = 0; mi < 4; mi++)
#pragma unroll
    for (int ni = 0; ni < 4; ni++) {
      int col = n0 + ni * 16 + l16;
      float bval = bias[col];
#pragma unroll
      for (int r = 0; r < 4; r++) {
        int row = m0 + mi * 16 + quad * 4 + r;
        out[(size_t)row * 512 + col] = acc[mi][ni][r] + bval + xres[(size_t)row * 512 + col];
      }
    }
}

// ---------------- stage 5: attention — r3-proven structure + T5 setprio -----
// (FROZEN since r6: 68.6-69.2us at normal clock; r8's 90us was profiling
// replay clock-state. dur/FETCH here serve as the run-state control.)
__global__ __launch_bounds__(256) void attn_kernel(const short* __restrict__ Q,
                                                   const short* __restrict__ Kmat,
                                                   const short* __restrict__ vTg,
                                                   short* __restrict__ O) {
  int tid = threadIdx.x;
  int w = tid >> 6, lane = tid & 63;
  int quad = lane >> 4, l16 = lane & 15;
  int lin = blockIdx.y * 128 + blockIdx.x;   // linear dispatch id (x fastest)
  int bh = (lin & 7) * 16 + (lin >> 7);      // XCD-chunked: xcd owns 16 bh
  int qt = (lin >> 3) & 15;                  // 16 same-bh blocks consecutive
  int b = bh >> 3, h = bh & 7;
  size_t base  = ((size_t)b * T_) * 1024 + (size_t)h * 64;
  size_t vbase = ((size_t)bh * 64) * 1024;
  size_t obase = ((size_t)b * T_) * 512 + (size_t)h * 64;
  int qrow0 = qt * 64;

  __shared__ __align__(16) char smem[32768 + 1024];
  short* KTb[2];
  KTb[0] = (short*)smem;                    // K dbuf half 0: 128 keys x 64d, swizzled
  KTb[1] = (short*)(smem + 16384);          // K dbuf half 1
  float* Lbuf = (float*)smem;               // epilogue union [q][d] pad 68 (17408B)
  float* denomL = (float*)(smem + 32768);   // outside both K buffers

  // Q as B-frags: B[k=d=quad*8+j][n=q=l16], 4 q-tiles x 2 d-halves
  short8 qf0[4], qf1[4];
#pragma unroll
  for (int g = 0; g < 4; g++) {
    const short* qp = Q + base + (size_t)(qrow0 + g * 16 + l16) * 1024 + quad * 8;
    qf0[g] = *(const short8*)qp;
    qf1[g] = *(const short8*)(qp + 32);
  }

  // K staging descriptors: lane's 16B block index bk = w*256 + n*64 + lane,
  // bank swizzle applied on the GLOBAL address side (LDS dst stays linear).
  const short* ksrc[4];
#pragma unroll
  for (int n = 0; n < 4; n++) {
    int bk = w * 256 + n * 64 + lane;
    int key = bk >> 3, jc = bk & 7;
    int dcol = jc ^ (key & 7);
    ksrc[n] = Kmat + base + (size_t)key * 1024 + dcol * 8;
  }

  // V fragment base: d-row = l16 (+f*16), key-slot = w*4+quad (vT layout)
  const short* vp0 = vTg + vbase + (size_t)l16 * 1024 + (w * 4 + quad) * 8;

  // K fragment LDS offsets (shorts), loop-invariant
  int l7 = l16 & 7;
  int kA0 = ((w * 16 + l16) * 8 + (quad ^ l7)) * 8;
  int kA1 = ((w * 16 + l16) * 8 + ((quad + 4) ^ l7)) * 8;
  int kB0 = kA0 + 4096;   // key + 64
  int kB1 = kA1 + 4096;

  f32x4 oacc[4][4] = {};   // O^T[d-tile f][q-tile g]
  float lsum[4] = {0.f, 0.f, 0.f, 0.f};

  // prologue: stage tile 0 into buffer 0
#pragma unroll
  for (int n = 0; n < 4; n++)
    gload_lds16(ksrc[n], KTb[0] + (w * 256 + n * 64) * 8);

#pragma unroll
  for (int t = 0; t < 8; t++) {
    short* KTc = KTb[t & 1];
    short* KTn = KTb[(t + 1) & 1];
    __syncthreads();   // drains vmcnt: K(t) staged; KTn's last readers done
    // V fragments for tile t: global->reg, issued first
    short8 vfr[4];
#pragma unroll
    for (int f = 0; f < 4; f++)
      vfr[f] = *(const short8*)(vp0 + (size_t)f * 16384 + t * 128);
    // stage K(t+1) into the other buffer — in flight across this whole phase
    if (t < 7) {
#pragma unroll
      for (int n = 0; n < 4; n++)
        gload_lds16(ksrc[n] + (size_t)(t + 1) * 131072, KTn + (w * 256 + n * 64) * 8);
    }
    // K fragments for tile t from LDS
    short8 ka0 = *(const short8*)(KTc + kA0);
    short8 ka1 = *(const short8*)(KTc + kA1);
    short8 kb0 = *(const short8*)(KTc + kB0);
    short8 kb1 = *(const short8*)(KTc + kB1);

#pragma unroll
    for (int g = 0; g < 4; g++) {
      f32x4 za = {}, zb = {};
      __builtin_amdgcn_s_setprio(1);
      za = __builtin_amdgcn_mfma_f32_16x16x32_bf16(ka0, qf0[g], za, 0, 0, 0);
      za = __builtin_amdgcn_mfma_f32_16x16x32_bf16(ka1, qf1[g], za, 0, 0, 0);
      zb = __builtin_amdgcn_mfma_f32_16x16x32_bf16(kb0, qf0[g], zb, 0, 0, 0);
      zb = __builtin_amdgcn_mfma_f32_16x16x32_bf16(kb1, qf1[g], zb, 0, 0, 0);
      __builtin_amdgcn_s_setprio(0);
      float pa0 = fexp2(za[0]), pa1 = fexp2(za[1]);
      float pa2 = fexp2(za[2]), pa3 = fexp2(za[3]);
      float pb0 = fexp2(zb[0]), pb1 = fexp2(zb[1]);
      float pb2 = fexp2(zb[2]), pb3 = fexp2(zb[3]);
      lsum[g] += (pa0 + pa1) + (pa2 + pa3) + ((pb0 + pb1) + (pb2 + pb3));
      short2 a01 = pack_bf2(pa0, pa1), a23 = pack_bf2(pa2, pa3);
      short2 b01 = pack_bf2(pb0, pb1), b23 = pack_bf2(pb2, pb3);
      short8 pf;
      pf[0] = a01.x; pf[1] = a01.y; pf[2] = a23.x; pf[3] = a23.y;
      pf[4] = b01.x; pf[5] = b01.y; pf[6] = b23.x; pf[7] = b23.y;
      __builtin_amdgcn_s_setprio(1);
#pragma unroll
      for (int f = 0; f < 4; f++)
        oacc[f][g] = __builtin_amdgcn_mfma_f32_16x16x32_bf16(vfr[f], pf, oacc[f][g], 0, 0, 0);
      __builtin_amdgcn_s_setprio(0);
    }
  }

  // per-lane lsum covers this wave's keys for query g*16+l16; sum over quads
#pragma unroll
  for (int g = 0; g < 4; g++) {
    lsum[g] += __shfl_xor(lsum[g], 16, 64);
    lsum[g] += __shfl_xor(lsum[g], 32, 64);
  }
  if (quad == 0) {
#pragma unroll
    for (int g = 0; g < 4; g++) denomL[w * 64 + g * 16 + l16] = lsum[g];
  }
  // sequential cross-wave accumulation of O^T into Lbuf (transposed to [q][d])
  for (int ww = 0; ww < 4; ww++) {
    __syncthreads();
    if (w == ww) {
#pragma unroll
      for (int g = 0; g < 4; g++)
#pragma unroll
        for (int f = 0; f < 4; f++) {
          float* p = &Lbuf[(g * 16 + l16) * 68 + f * 16 + quad * 4];
          if (ww == 0) *(f32x4*)p = oacc[f][g];
          else         *(f32x4*)p = *(f32x4*)p + oacc[f][g];
        }
    }
  }
  __syncthreads();

  // coalesced writeout: thread -> (q = tid/4, 16-wide d segment)
  int q = tid >> 2, seg = tid & 3;
  float dn = denomL[q] + denomL[64 + q] + denomL[128 + q] + denomL[192 + q];
  float rinv = __frcp_rn(dn);
  const float* row = &Lbuf[q * 68 + seg * 16];
  short8 o0, o1;
#pragma unroll
  for (int i = 0; i < 8; i++) o0[i] = f2bf(row[i] * rinv);
#pragma unroll
  for (int i = 0; i < 8; i++) o1[i] = f2bf(row[8 + i] * rinv);
  short* op = O + obase + (size_t)(qrow0 + q) * 512 + seg * 16;
  *(short8*)op = o0;
  *(short8*)(op + 8) = o1;
}

extern "C" void kernel_launch(void* const* d_in, const int* in_sizes, int n_in,
                              void* d_out, int out_size, void* d_ws, size_t ws_size,
                              hipStream_t stream) {
  const float* x     = (const float*)d_in[0];
  const float* gamma = (const float*)d_in[1];
  const float* beta  = (const float*)d_in[2];
  const float* wq    = (const float*)d_in[3];
  const float* bq    = (const float*)d_in[4];
  const float* wk    = (const float*)d_in[5];
  const float* bk    = (const float*)d_in[6];
  const float* wv    = (const float*)d_in[7];
  const float* bv    = (const float*)d_in[8];
  const float* wo    = (const float*)d_in[9];
  const float* bo    = (const float*)d_in[10];
  float* out = (float*)d_out;

  char* ws = (char*)d_ws;
  const size_t XN_ELEMS = (size_t)B_ * T_ * C_;
  size_t off = 0;
  off += 256;                                              // (reserved)
  float2* partials = (float2*)(ws + off); off += 16 * 64 * sizeof(float2);
  short* xn    = (short*)(ws + off); off += XN_ELEMS * 2;
  short* wqkvT = (short*)(ws + off); off += (size_t)1536 * 512 * 2;
  short* woT   = (short*)(ws + off); off += (size_t)512 * 512 * 2;
  short* qkv   = (short*)(ws + off); off += (size_t)B_ * T_ * 1024 * 2;  // Q|K compact
  short* vTb   = (short*)(ws + off); off += XN_ELEMS * 2;
  short* ao    = (short*)(ws + off); off += XN_ELEMS * 2;

  stats1_trans_kernel<<<5120, 256, 0, stream>>>(x, partials, wq, wk, wv, wo, wqkvT, woT);
  norm_kernel<<<8192, 256, 0, stream>>>(x, gamma, beta, partials, xn);

  gemm_qkv<<<dim3(12, 128), 256, 0, stream>>>(xn, wqkvT, bq, bk, bv, qkv, vTb);

  attn_kernel<<<dim3(128, 16), 256, 0, stream>>>(qkv, qkv + 512, vTb, ao);

  gemm_out<<<dim3(4, 128), 256, 0, stream>>>(ao, woT, bo, x, out);
}

// Round 12
// 227.664 us; speedup vs baseline: 1.1104x; 1.0141x over previous
//
#include <hip/hip_runtime.h>
#include <hip/hip_bf16.h>

typedef __attribute__((ext_vector_type(8))) short short8;
typedef __attribute__((ext_vector_type(4))) short short4v;
typedef __attribute__((ext_vector_type(4))) float f32x4;

#define B_ 16
#define T_ 1024
#define C_ 512
#define NH 8
#define HD 64

__device__ __forceinline__ short f2bf(float f) {
  union { float f; unsigned u; } v;
  v.f = f;
  unsigned r = v.u + 0x7fffu + ((v.u >> 16) & 1u);
  return (short)(r >> 16);
}

__device__ __forceinline__ short2 pack_bf2(float a, float b) {
  __hip_bfloat162 t = __float22bfloat162_rn(make_float2(a, b));
  short2 r;
  __builtin_memcpy(&r, &t, 4);
  return r;
}

// bare v_exp_f32: computes 2^x. The softmax scale folds log2(e) into Q
// at gemm_qkv, so scores arrive pre-multiplied — saves one v_mul per exp.
__device__ __forceinline__ float fexp2(float x) {
  float r;
  asm("v_exp_f32 %0, %1" : "=v"(r) : "v"(x));
  return r;
}

__device__ __forceinline__ void gload_lds16(const short* g, short* l) {
  __builtin_amdgcn_global_load_lds(
      (const __attribute__((address_space(1))) void*)g,
      (__attribute__((address_space(3))) void*)l, 16, 0, 0);
}

// ---------------- stage 1: partial sums + weight transpose (merged launch) ----
// Blocks 0..1023: GroupNorm partial sums (chunk = blk&63, b = blk>>6).
// Blocks 1024..5119: fp32 -> bf16 transposed weight prep (former kernel).
// Branch is block-uniform, so the barrier inside the stats path stays legal.
__global__ __launch_bounds__(256) void stats1_trans_kernel(
    const float* __restrict__ x, float2* __restrict__ partials,
    const float* __restrict__ wq, const float* __restrict__ wk,
    const float* __restrict__ wv, const float* __restrict__ wo,
    short* __restrict__ wqkvT, short* __restrict__ woT) {
  int blk = blockIdx.x;
  int tid = threadIdx.x;
  if (blk < 1024) {
    int chunk = blk & 63;
    int b = blk >> 6;
    const float4* xb = (const float4*)(x + (size_t)b * 524288 + (size_t)chunk * 8192);
    float s = 0.f, s2 = 0.f;
#pragma unroll
    for (int i = 0; i < 8; i++) {
      float4 v = xb[tid + i * 256];
      s  += v.x + v.y + v.z + v.w;
      s2 += v.x * v.x + v.y * v.y + v.z * v.z + v.w * v.w;
    }
    __shared__ float ls[256], ls2[256];
    ls[tid] = s; ls2[tid] = s2;
    __syncthreads();
    for (int o = 128; o > 0; o >>= 1) {
      if (tid < o) { ls[tid] += ls[tid + o]; ls2[tid] += ls2[tid + o]; }
      __syncthreads();
    }
    if (tid == 0) partials[b * 64 + chunk] = make_float2(ls[0], ls2[0]);
  } else {
    int o = (blk - 1024) * 256 + tid;
    int sel = o >> 18;
    int oo = o & 262143;
    int k = oo >> 9, n = oo & 511;
    const float* w = (sel == 0) ? wq : (sel == 1) ? wk : (sel == 2) ? wv : wo;
    float val = w[oo];
    if (sel < 3) wqkvT[((size_t)(sel * 512 + n)) * 512 + k] = f2bf(val);
    else         woT[(size_t)n * 512 + k] = f2bf(val);
  }
}

// ---------------- stage 2: normalize + affine -> bf16 (stats2 fused) --------
// r12: grid 8192 -> 2048 blocks, 4 float4s per thread (Guideline 11) — cuts
// redundant per-block stats reductions 512->128 per sample + launch tail.
// Block spans ONE sample: 128 blocks x 4096 floats per sample (b = blk>>7).
__global__ __launch_bounds__(256) void norm_kernel(const float* __restrict__ x,
                                                   const float* __restrict__ gamma,
                                                   const float* __restrict__ beta,
                                                   const float2* __restrict__ partials,
                                                   short* __restrict__ xn) {
  __shared__ float sm[2];
  int tid = threadIdx.x;
  int b = blockIdx.x >> 7;
  if (tid < 64) {
    float2 p = partials[b * 64 + tid];
    float s = p.x, s2 = p.y;
#pragma unroll
    for (int off = 1; off < 64; off <<= 1) {
      s  += __shfl_xor(s,  off, 64);
      s2 += __shfl_xor(s2, off, 64);
    }
    if (tid == 0) {
      float mean = s * (1.f / 524288.f);
      float var  = s2 * (1.f / 524288.f) - mean * mean;
      sm[0] = mean;
      sm[1] = rsqrtf(var + 1e-5f);
    }
  }
  __syncthreads();
  float mean = sm[0], rstd = sm[1];
#pragma unroll
  for (int it = 0; it < 4; it++) {
    size_t i4 = (size_t)blockIdx.x * 1024 + it * 256 + tid;
    float4 v = ((const float4*)x)[i4];
    int c = (int)((i4 * 4) & 511);
    short4v o;
    o[0] = f2bf((v.x - mean) * rstd * gamma[c + 0] + beta[c + 0]);
    o[1] = f2bf((v.y - mean) * rstd * gamma[c + 1] + beta[c + 1]);
    o[2] = f2bf((v.z - mean) * rstd * gamma[c + 2] + beta[c + 2]);
    o[3] = f2bf((v.w - mean) * rstd * gamma[c + 3] + beta[c + 3]);
    ((short4v*)xn)[i4] = o;
  }
}

// ---------------- stage 4: fused QKV GEMM (BK=64 + XCD swizzle; r10-proven) --
__global__ __launch_bounds__(256) void gemm_qkv(const short* __restrict__ A,
                                                const short* __restrict__ Bt,
                                                const float* __restrict__ bq,
                                                const float* __restrict__ bk,
                                                const float* __restrict__ bv,
                                                short* __restrict__ C,
                                                short* __restrict__ vT) {
  __shared__ __align__(16) short As[2][128 * 32];
  __shared__ __align__(16) short Bs[2][128 * 32];
  int tid = threadIdx.x;
  int w = tid >> 6, lane = tid & 63;
  int quad = lane >> 4, l16 = lane & 15;
  int mw = (w >> 1) * 64, nw = (w & 1) * 64;
  int lin = blockIdx.y * 12 + blockIdx.x;   // linear dispatch id (x fastest)
  int my = (lin & 7) + ((lin / 96) << 3);   // M-tile 0..127 (XCD-chunked)
  int mx = (lin >> 3) % 12;                 // N-tile 0..11
  int seg = (mx * 128) >> 9;
  const float* bias = (seg == 0) ? bq : (seg == 1) ? bk : bv;
  float smul = (seg == 0) ? 0.18033688011112042f : 1.0f;
  const short* Atile = A + (size_t)(my * 128) * 512;
  const short* Btile = Bt + (size_t)(mx * 128) * 512;
  int srow = (w << 4) + (lane >> 2);
  int scol = (lane & 3) * 8;
  f32x4 acc[4][4] = {};
  for (int k0 = 0; k0 < 512; k0 += 64) {
    __syncthreads();
    gload_lds16(&Atile[(size_t)srow * 512 + k0 + scol],             &As[0][w * 512]);
    gload_lds16(&Atile[(size_t)(srow + 64) * 512 + k0 + scol],      &As[0][2048 + w * 512]);
    gload_lds16(&Atile[(size_t)srow * 512 + k0 + 32 + scol],        &As[1][w * 512]);
    gload_lds16(&Atile[(size_t)(srow + 64) * 512 + k0 + 32 + scol], &As[1][2048 + w * 512]);
    gload_lds16(&Btile[(size_t)srow * 512 + k0 + scol],             &Bs[0][w * 512]);
    gload_lds16(&Btile[(size_t)(srow + 64) * 512 + k0 + scol],      &Bs[0][2048 + w * 512]);
    gload_lds16(&Btile[(size_t)srow * 512 + k0 + 32 + scol],        &Bs[1][w * 512]);
    gload_lds16(&Btile[(size_t)(srow + 64) * 512 + k0 + 32 + scol], &Bs[1][2048 + w * 512]);
    __syncthreads();
    short8 af[2][4], bf[2][4];
#pragma unroll
    for (int s = 0; s < 2; s++)
#pragma unroll
      for (int i = 0; i < 4; i++) {
        af[s][i] = *(const short8*)(&As[s][(mw + i * 16 + l16) * 32 + quad * 8]);
        bf[s][i] = *(const short8*)(&Bs[s][(nw + i * 16 + l16) * 32 + quad * 8]);
      }
#pragma unroll
    for (int mi = 0; mi < 4; mi++)
#pragma unroll
      for (int ni = 0; ni < 4; ni++) {
        acc[mi][ni] = __builtin_amdgcn_mfma_f32_16x16x32_bf16(af[0][mi], bf[0][ni], acc[mi][ni], 0, 0, 0);
        acc[mi][ni] = __builtin_amdgcn_mfma_f32_16x16x32_bf16(af[1][mi], bf[1][ni], acc[mi][ni], 0, 0, 0);
      }
  }
  int m0 = my * 128 + mw;
  int n0 = mx * 128 + nw;
  if (seg < 2) {
#pragma unroll
    for (int mi = 0; mi < 4; mi++)
#pragma unroll
      for (int ni = 0; ni < 4; ni++) {
        int col = n0 + ni * 16 + l16;        // 0..1023 (Q|K)
        float bval = bias[col & 511];
#pragma unroll
        for (int r = 0; r < 4; r++) {
          int row = m0 + mi * 16 + quad * 4 + r;
          C[(size_t)row * 1024 + col] = f2bf((acc[mi][ni][r] + bval) * smul);
        }
      }
  } else {
    // V -> vT[(b*8+h)*64 + d][chunk*128 + slot]; slot = mi*32+quad*8+half*4+r
    int b = my >> 3;
    int chunk = my & 7;
    int half = mw >> 6;                      // 0 or 1
#pragma unroll
    for (int mi = 0; mi < 4; mi++)
#pragma unroll
      for (int ni = 0; ni < 4; ni++) {
        int c = (n0 - 1024) + ni * 16 + l16; // 0..511 v-col
        int h = c >> 6, d = c & 63;
        float bval = bias[c];
        short4v pk;
#pragma unroll
        for (int r = 0; r < 4; r++) pk[r] = f2bf(acc[mi][ni][r] + bval);
        short* dst = vT + ((size_t)((b * 8 + h) * 64 + d)) * 1024
                        + chunk * 128 + mi * 32 + quad * 8 + half * 4;
        *(short4v*)dst = pk;
      }
  }
}

// ---------------- stage 6: GEMM + bias + residual (fp32 out; r10-proven) ----
__global__ __launch_bounds__(256) void gemm_out(const short* __restrict__ A,
                                                const short* __restrict__ Bt,
                                                const float* __restrict__ bias,
                                                const float* __restrict__ xres,
                                                float* __restrict__ out) {
  __shared__ __align__(16) short As[2][128 * 32];
  __shared__ __align__(16) short Bs[2][128 * 32];
  int tid = threadIdx.x;
  int w = tid >> 6, lane = tid & 63;
  int quad = lane >> 4, l16 = lane & 15;
  int mw = (w >> 1) * 64, nw = (w & 1) * 64;
  int lin = blockIdx.y * 4 + blockIdx.x;    // linear dispatch id (x fastest)
  int my = (lin & 7) + ((lin / 32) << 3);   // M-tile 0..127 (XCD-chunked)
  int mx = (lin >> 3) & 3;                  // N-tile 0..3
  const short* Atile = A + (size_t)(my * 128) * 512;
  const short* Btile = Bt + (size_t)(mx * 128) * 512;
  int srow = (w << 4) + (lane >> 2);
  int scol = (lane & 3) * 8;
  f32x4 acc[4][4] = {};
  for (int k0 = 0; k0 < 512; k0 += 64) {
    __syncthreads();
    gload_lds16(&Atile[(size_t)srow * 512 + k0 + scol],             &As[0][w * 512]);
    gload_lds16(&Atile[(size_t)(srow + 64) * 512 + k0 + scol],      &As[0][2048 + w * 512]);
    gload_lds16(&Atile[(size_t)srow * 512 + k0 + 32 + scol],        &As[1][w * 512]);
    gload_lds16(&Atile[(size_t)(srow + 64) * 512 + k0 + 32 + scol], &As[1][2048 + w * 512]);
    gload_lds16(&Btile[(size_t)srow * 512 + k0 + scol],             &Bs[0][w * 512]);
    gload_lds16(&Btile[(size_t)(srow + 64) * 512 + k0 + scol],      &Bs[0][2048 + w * 512]);
    gload_lds16(&Btile[(size_t)srow * 512 + k0 + 32 + scol],        &Bs[1][w * 512]);
    gload_lds16(&Btile[(size_t)(srow + 64) * 512 + k0 + 32 + scol], &Bs[1][2048 + w * 512]);
    __syncthreads();
    short8 af[2][4], bf[2][4];
#pragma unroll
    for (int s = 0; s < 2; s++)
#pragma unroll
      for (int i = 0; i < 4; i++) {
        af[s][i] = *(const short8*)(&As[s][(mw + i * 16 + l16) * 32 + quad * 8]);
        bf[s][i] = *(const short8*)(&Bs[s][(nw + i * 16 + l16) * 32 + quad * 8]);
      }
#pragma unroll
    for (int mi = 0; mi < 4; mi++)
#pragma unroll
      for (int ni = 0; ni < 4; ni++) {
        acc[mi][ni] = __builtin_amdgcn_mfma_f32_16x16x32_bf16(af[0][mi], bf[0][ni], acc[mi][ni], 0, 0, 0);
        acc[mi][ni] = __builtin_amdgcn_mfma_f32_16x16x32_bf16(af[1][mi], bf[1][ni], acc[mi][ni], 0, 0, 0);
      }
  }
  int m0 = my * 128 + mw;
  int n0 = mx * 128 + nw;
#pragma unroll
  for (int mi = 0; mi < 4; mi++)
#pragma unroll
    for (int ni = 0; ni < 4; ni++) {
      int col = n0 + ni * 16 + l16;
      float bval = bias[col];
#pragma unroll
      for (int r = 0; r < 4; r++) {
        int row = m0 + mi * 16 + quad * 4 + r;
        out[(size_t)row * 512 + col] = acc[mi][ni][r] + bval + xres[(size_t)row * 512 + col];
      }
    }
}

// ---------------- stage 5: attention — r10 byte-exact (FROZEN) --------------
// 4-wave, 2-phase pipelined K-LDS, V direct, XCD-chunked, T5 setprio.
// 68.6-69.2us at normal clock. The 8-wave merged-qt variant is ABANDONED:
// failed twice (r4 NaN, r11 absmax 0.18) with no root cause identifiable by
// inspection across three full index audits. Do not retry without a
// single-variant debug harness.
__global__ __launch_bounds__(256) void attn_kernel(const short* __restrict__ Q,
                                                   const short* __restrict__ Kmat,
                                                   const short* __restrict__ vTg,
                                                   short* __restrict__ O) {
  int tid = threadIdx.x;
  int w = tid >> 6, lane = tid & 63;
  int quad = lane >> 4, l16 = lane & 15;
  int lin = blockIdx.y * 128 + blockIdx.x;   // linear dispatch id (x fastest)
  int bh = (lin & 7) * 16 + (lin >> 7);      // XCD-chunked: xcd owns 16 bh
  int qt = (lin >> 3) & 15;                  // 16 same-bh blocks consecutive
  int b = bh >> 3, h = bh & 7;
  size_t base  = ((size_t)b * T_) * 1024 + (size_t)h * 64;
  size_t vbase = ((size_t)bh * 64) * 1024;
  size_t obase = ((size_t)b * T_) * 512 + (size_t)h * 64;
  int qrow0 = qt * 64;

  __shared__ __align__(16) char smem[32768 + 1024];
  short* KTb[2];
  KTb[0] = (short*)smem;                    // K dbuf half 0: 128 keys x 64d, swizzled
  KTb[1] = (short*)(smem + 16384);          // K dbuf half 1
  float* Lbuf = (float*)smem;               // epilogue union [q][d] pad 68 (17408B)
  float* denomL = (float*)(smem + 32768);   // outside both K buffers

  // Q as B-frags: B[k=d=quad*8+j][n=q=l16], 4 q-tiles x 2 d-halves
  short8 qf0[4], qf1[4];
#pragma unroll
  for (int g = 0; g < 4; g++) {
    const short* qp = Q + base + (size_t)(qrow0 + g * 16 + l16) * 1024 + quad * 8;
    qf0[g] = *(const short8*)qp;
    qf1[g] = *(const short8*)(qp + 32);
  }

  // K staging descriptors: lane's 16B block index bk = w*256 + n*64 + lane,
  // bank swizzle applied on the GLOBAL address side (LDS dst stays linear).
  const short* ksrc[4];
#pragma unroll
  for (int n = 0; n < 4; n++) {
    int bk = w * 256 + n * 64 + lane;
    int key = bk >> 3, jc = bk & 7;
    int dcol = jc ^ (key & 7);
    ksrc[n] = Kmat + base + (size_t)key * 1024 + dcol * 8;
  }

  // V fragment base: d-row = l16 (+f*16), key-slot = w*4+quad (vT layout)
  const short* vp0 = vTg + vbase + (size_t)l16 * 1024 + (w * 4 + quad) * 8;

  // K fragment LDS offsets (shorts), loop-invariant
  int l7 = l16 & 7;
  int kA0 = ((w * 16 + l16) * 8 + (quad ^ l7)) * 8;
  int kA1 = ((w * 16 + l16) * 8 + ((quad + 4) ^ l7)) * 8;
  int kB0 = kA0 + 4096;   // key + 64
  int kB1 = kA1 + 4096;

  f32x4 oacc[4][4] = {};   // O^T[d-tile f][q-tile g]
  float lsum[4] = {0.f, 0.f, 0.f, 0.f};

  // prologue: stage tile 0 into buffer 0
#pragma unroll
  for (int n = 0; n < 4; n++)
    gload_lds16(ksrc[n], KTb[0] + (w * 256 + n * 64) * 8);

#pragma unroll
  for (int t = 0; t < 8; t++) {
    short* KTc = KTb[t & 1];
    short* KTn = KTb[(t + 1) & 1];
    __syncthreads();   // drains vmcnt: K(t) staged; KTn's last readers done
    // V fragments for tile t: global->reg, issued first
    short8 vfr[4];
#pragma unroll
    for (int f = 0; f < 4; f++)
      vfr[f] = *(const short8*)(vp0 + (size_t)f * 16384 + t * 128);
    // stage K(t+1) into the other buffer — in flight across this whole phase
    if (t < 7) {
#pragma unroll
      for (int n = 0; n < 4; n++)
        gload_lds16(ksrc[n] + (size_t)(t + 1) * 131072, KTn + (w * 256 + n * 64) * 8);
    }
    // K fragments for tile t from LDS
    short8 ka0 = *(const short8*)(KTc + kA0);
    short8 ka1 = *(const short8*)(KTc + kA1);
    short8 kb0 = *(const short8*)(KTc + kB0);
    short8 kb1 = *(const short8*)(KTc + kB1);

#pragma unroll
    for (int g = 0; g < 4; g++) {
      f32x4 za = {}, zb = {};
      __builtin_amdgcn_s_setprio(1);
      za = __builtin_amdgcn_mfma_f32_16x16x32_bf16(ka0, qf0[g], za, 0, 0, 0);
      za = __builtin_amdgcn_mfma_f32_16x16x32_bf16(ka1, qf1[g], za, 0, 0, 0);
      zb = __builtin_amdgcn_mfma_f32_16x16x32_bf16(kb0, qf0[g], zb, 0, 0, 0);
      zb = __builtin_amdgcn_mfma_f32_16x16x32_bf16(kb1, qf1[g], zb, 0, 0, 0);
      __builtin_amdgcn_s_setprio(0);
      float pa0 = fexp2(za[0]), pa1 = fexp2(za[1]);
      float pa2 = fexp2(za[2]), pa3 = fexp2(za[3]);
      float pb0 = fexp2(zb[0]), pb1 = fexp2(zb[1]);
      float pb2 = fexp2(zb[2]), pb3 = fexp2(zb[3]);
      lsum[g] += (pa0 + pa1) + (pa2 + pa3) + ((pb0 + pb1) + (pb2 + pb3));
      short2 a01 = pack_bf2(pa0, pa1), a23 = pack_bf2(pa2, pa3);
      short2 b01 = pack_bf2(pb0, pb1), b23 = pack_bf2(pb2, pb3);
      short8 pf;
      pf[0] = a01.x; pf[1] = a01.y; pf[2] = a23.x; pf[3] = a23.y;
      pf[4] = b01.x; pf[5] = b01.y; pf[6] = b23.x; pf[7] = b23.y;
      __builtin_amdgcn_s_setprio(1);
#pragma unroll
      for (int f = 0; f < 4; f++)
        oacc[f][g] = __builtin_amdgcn_mfma_f32_16x16x32_bf16(vfr[f], pf, oacc[f][g], 0, 0, 0);
      __builtin_amdgcn_s_setprio(0);
    }
  }

  // per-lane lsum covers this wave's keys for query g*16+l16; sum over quads
#pragma unroll
  for (int g = 0; g < 4; g++) {
    lsum[g] += __shfl_xor(lsum[g], 16, 64);
    lsum[g] += __shfl_xor(lsum[g], 32, 64);
  }
  if (quad == 0) {
#pragma unroll
    for (int g = 0; g < 4; g++) denomL[w * 64 + g * 16 + l16] = lsum[g];
  }
  // sequential cross-wave accumulation of O^T into Lbuf (transposed to [q][d])
  for (int ww = 0; ww < 4; ww++) {
    __syncthreads();
    if (w == ww) {
#pragma unroll
      for (int g = 0; g < 4; g++)
#pragma unroll
        for (int f = 0; f < 4; f++) {
          float* p = &Lbuf[(g * 16 + l16) * 68 + f * 16 + quad * 4];
          if (ww == 0) *(f32x4*)p = oacc[f][g];
          else         *(f32x4*)p = *(f32x4*)p + oacc[f][g];
        }
    }
  }
  __syncthreads();

  // coalesced writeout: thread -> (q = tid/4, 16-wide d segment)
  int q = tid >> 2, seg = tid & 3;
  float dn = denomL[q] + denomL[64 + q] + denomL[128 + q] + denomL[192 + q];
  float rinv = __frcp_rn(dn);
  const float* row = &Lbuf[q * 68 + seg * 16];
  short8 o0, o1;
#pragma unroll
  for (int i = 0; i < 8; i++) o0[i] = f2bf(row[i] * rinv);
#pragma unroll
  for (int i = 0; i < 8; i++) o1[i] = f2bf(row[8 + i] * rinv);
  short* op = O + obase + (size_t)(qrow0 + q) * 512 + seg * 16;
  *(short8*)op = o0;
  *(short8*)(op + 8) = o1;
}

extern "C" void kernel_launch(void* const* d_in, const int* in_sizes, int n_in,
                              void* d_out, int out_size, void* d_ws, size_t ws_size,
                              hipStream_t stream) {
  const float* x     = (const float*)d_in[0];
  const float* gamma = (const float*)d_in[1];
  const float* beta  = (const float*)d_in[2];
  const float* wq    = (const float*)d_in[3];
  const float* bq    = (const float*)d_in[4];
  const float* wk    = (const float*)d_in[5];
  const float* bk    = (const float*)d_in[6];
  const float* wv    = (const float*)d_in[7];
  const float* bv    = (const float*)d_in[8];
  const float* wo    = (const float*)d_in[9];
  const float* bo    = (const float*)d_in[10];
  float* out = (float*)d_out;

  char* ws = (char*)d_ws;
  const size_t XN_ELEMS = (size_t)B_ * T_ * C_;
  size_t off = 0;
  off += 256;                                              // (reserved)
  float2* partials = (float2*)(ws + off); off += 16 * 64 * sizeof(float2);
  short* xn    = (short*)(ws + off); off += XN_ELEMS * 2;
  short* wqkvT = (short*)(ws + off); off += (size_t)1536 * 512 * 2;
  short* woT   = (short*)(ws + off); off += (size_t)512 * 512 * 2;
  short* qkv   = (short*)(ws + off); off += (size_t)B_ * T_ * 1024 * 2;  // Q|K compact
  short* vTb   = (short*)(ws + off); off += XN_ELEMS * 2;
  short* ao    = (short*)(ws + off); off += XN_ELEMS * 2;

  stats1_trans_kernel<<<5120, 256, 0, stream>>>(x, partials, wq, wk, wv, wo, wqkvT, woT);
  norm_kernel<<<2048, 256, 0, stream>>>(x, gamma, beta, partials, xn);

  gemm_qkv<<<dim3(12, 128), 256, 0, stream>>>(xn, wqkvT, bq, bk, bv, qkv, vTb);

  attn_kernel<<<dim3(128, 16), 256, 0, stream>>>(qkv, qkv + 512, vTb, ao);

  gemm_out<<<dim3(4, 128), 256, 0, stream>>>(ao, woT, bo, x, out);
}

// Round 13
// 225.690 us; speedup vs baseline: 1.1201x; 1.0087x over previous
//
#include <hip/hip_runtime.h>
#include <hip/hip_bf16.h>

typedef __attribute__((ext_vector_type(8))) short short8;
typedef __attribute__((ext_vector_type(4))) short short4v;
typedef __attribute__((ext_vector_type(4))) float f32x4;

#define B_ 16
#define T_ 1024
#define C_ 512
#define NH 8
#define HD 64

__device__ __forceinline__ short f2bf(float f) {
  union { float f; unsigned u; } v;
  v.f = f;
  unsigned r = v.u + 0x7fffu + ((v.u >> 16) & 1u);
  return (short)(r >> 16);
}

__device__ __forceinline__ short2 pack_bf2(float a, float b) {
  __hip_bfloat162 t = __float22bfloat162_rn(make_float2(a, b));
  short2 r;
  __builtin_memcpy(&r, &t, 4);
  return r;
}

// bare v_exp_f32: computes 2^x. The softmax scale folds log2(e) into Q
// at gemm_qkv, so scores arrive pre-multiplied — saves one v_mul per exp.
__device__ __forceinline__ float fexp2(float x) {
  float r;
  asm("v_exp_f32 %0, %1" : "=v"(r) : "v"(x));
  return r;
}

__device__ __forceinline__ void gload_lds16(const short* g, short* l) {
  __builtin_amdgcn_global_load_lds(
      (const __attribute__((address_space(1))) void*)g,
      (__attribute__((address_space(3))) void*)l, 16, 0, 0);
}

// ---------------- stage 1: partial sums + weight transpose (merged launch) ----
// Blocks 0..1023: GroupNorm partial sums (chunk = blk&63, b = blk>>6).
// Blocks 1024..5119: fp32 -> bf16 transposed weight prep (former kernel).
// Branch is block-uniform, so the barrier inside the stats path stays legal.
__global__ __launch_bounds__(256) void stats1_trans_kernel(
    const float* __restrict__ x, float2* __restrict__ partials,
    const float* __restrict__ wq, const float* __restrict__ wk,
    const float* __restrict__ wv, const float* __restrict__ wo,
    short* __restrict__ wqkvT, short* __restrict__ woT) {
  int blk = blockIdx.x;
  int tid = threadIdx.x;
  if (blk < 1024) {
    int chunk = blk & 63;
    int b = blk >> 6;
    const float4* xb = (const float4*)(x + (size_t)b * 524288 + (size_t)chunk * 8192);
    float s = 0.f, s2 = 0.f;
#pragma unroll
    for (int i = 0; i < 8; i++) {
      float4 v = xb[tid + i * 256];
      s  += v.x + v.y + v.z + v.w;
      s2 += v.x * v.x + v.y * v.y + v.z * v.z + v.w * v.w;
    }
    __shared__ float ls[256], ls2[256];
    ls[tid] = s; ls2[tid] = s2;
    __syncthreads();
    for (int o = 128; o > 0; o >>= 1) {
      if (tid < o) { ls[tid] += ls[tid + o]; ls2[tid] += ls2[tid + o]; }
      __syncthreads();
    }
    if (tid == 0) partials[b * 64 + chunk] = make_float2(ls[0], ls2[0]);
  } else {
    int o = (blk - 1024) * 256 + tid;
    int sel = o >> 18;
    int oo = o & 262143;
    int k = oo >> 9, n = oo & 511;
    const float* w = (sel == 0) ? wq : (sel == 1) ? wk : (sel == 2) ? wv : wo;
    float val = w[oo];
    if (sel < 3) wqkvT[((size_t)(sel * 512 + n)) * 512 + k] = f2bf(val);
    else         woT[(size_t)n * 512 + k] = f2bf(val);
  }
}

// ---------------- stage 2: normalize + affine -> bf16 (stats2 fused) --------
// r12-proven: 2048 blocks, 4 float4s/thread; block spans one sample (b=blk>>7).
__global__ __launch_bounds__(256) void norm_kernel(const float* __restrict__ x,
                                                   const float* __restrict__ gamma,
                                                   const float* __restrict__ beta,
                                                   const float2* __restrict__ partials,
                                                   short* __restrict__ xn) {
  __shared__ float sm[2];
  int tid = threadIdx.x;
  int b = blockIdx.x >> 7;
  if (tid < 64) {
    float2 p = partials[b * 64 + tid];
    float s = p.x, s2 = p.y;
#pragma unroll
    for (int off = 1; off < 64; off <<= 1) {
      s  += __shfl_xor(s,  off, 64);
      s2 += __shfl_xor(s2, off, 64);
    }
    if (tid == 0) {
      float mean = s * (1.f / 524288.f);
      float var  = s2 * (1.f / 524288.f) - mean * mean;
      sm[0] = mean;
      sm[1] = rsqrtf(var + 1e-5f);
    }
  }
  __syncthreads();
  float mean = sm[0], rstd = sm[1];
#pragma unroll
  for (int it = 0; it < 4; it++) {
    size_t i4 = (size_t)blockIdx.x * 1024 + it * 256 + tid;
    float4 v = ((const float4*)x)[i4];
    int c = (int)((i4 * 4) & 511);
    short4v o;
    o[0] = f2bf((v.x - mean) * rstd * gamma[c + 0] + beta[c + 0]);
    o[1] = f2bf((v.y - mean) * rstd * gamma[c + 1] + beta[c + 1]);
    o[2] = f2bf((v.z - mean) * rstd * gamma[c + 2] + beta[c + 2]);
    o[3] = f2bf((v.w - mean) * rstd * gamma[c + 3] + beta[c + 3]);
    ((short4v*)xn)[i4] = o;
  }
}

// ---------------- stage 4: fused QKV GEMM (BK=64 + XCD swizzle; r10-proven) --
__global__ __launch_bounds__(256) void gemm_qkv(const short* __restrict__ A,
                                                const short* __restrict__ Bt,
                                                const float* __restrict__ bq,
                                                const float* __restrict__ bk,
                                                const float* __restrict__ bv,
                                                short* __restrict__ C,
                                                short* __restrict__ vT) {
  __shared__ __align__(16) short As[2][128 * 32];
  __shared__ __align__(16) short Bs[2][128 * 32];
  int tid = threadIdx.x;
  int w = tid >> 6, lane = tid & 63;
  int quad = lane >> 4, l16 = lane & 15;
  int mw = (w >> 1) * 64, nw = (w & 1) * 64;
  int lin = blockIdx.y * 12 + blockIdx.x;   // linear dispatch id (x fastest)
  int my = (lin & 7) + ((lin / 96) << 3);   // M-tile 0..127 (XCD-chunked)
  int mx = (lin >> 3) % 12;                 // N-tile 0..11
  int seg = (mx * 128) >> 9;
  const float* bias = (seg == 0) ? bq : (seg == 1) ? bk : bv;
  float smul = (seg == 0) ? 0.18033688011112042f : 1.0f;
  const short* Atile = A + (size_t)(my * 128) * 512;
  const short* Btile = Bt + (size_t)(mx * 128) * 512;
  int srow = (w << 4) + (lane >> 2);
  int scol = (lane & 3) * 8;
  f32x4 acc[4][4] = {};
  for (int k0 = 0; k0 < 512; k0 += 64) {
    __syncthreads();
    gload_lds16(&Atile[(size_t)srow * 512 + k0 + scol],             &As[0][w * 512]);
    gload_lds16(&Atile[(size_t)(srow + 64) * 512 + k0 + scol],      &As[0][2048 + w * 512]);
    gload_lds16(&Atile[(size_t)srow * 512 + k0 + 32 + scol],        &As[1][w * 512]);
    gload_lds16(&Atile[(size_t)(srow + 64) * 512 + k0 + 32 + scol], &As[1][2048 + w * 512]);
    gload_lds16(&Btile[(size_t)srow * 512 + k0 + scol],             &Bs[0][w * 512]);
    gload_lds16(&Btile[(size_t)(srow + 64) * 512 + k0 + scol],      &Bs[0][2048 + w * 512]);
    gload_lds16(&Btile[(size_t)srow * 512 + k0 + 32 + scol],        &Bs[1][w * 512]);
    gload_lds16(&Btile[(size_t)(srow + 64) * 512 + k0 + 32 + scol], &Bs[1][2048 + w * 512]);
    __syncthreads();
    short8 af[2][4], bf[2][4];
#pragma unroll
    for (int s = 0; s < 2; s++)
#pragma unroll
      for (int i = 0; i < 4; i++) {
        af[s][i] = *(const short8*)(&As[s][(mw + i * 16 + l16) * 32 + quad * 8]);
        bf[s][i] = *(const short8*)(&Bs[s][(nw + i * 16 + l16) * 32 + quad * 8]);
      }
#pragma unroll
    for (int mi = 0; mi < 4; mi++)
#pragma unroll
      for (int ni = 0; ni < 4; ni++) {
        acc[mi][ni] = __builtin_amdgcn_mfma_f32_16x16x32_bf16(af[0][mi], bf[0][ni], acc[mi][ni], 0, 0, 0);
        acc[mi][ni] = __builtin_amdgcn_mfma_f32_16x16x32_bf16(af[1][mi], bf[1][ni], acc[mi][ni], 0, 0, 0);
      }
  }
  int m0 = my * 128 + mw;
  int n0 = mx * 128 + nw;
  if (seg < 2) {
#pragma unroll
    for (int mi = 0; mi < 4; mi++)
#pragma unroll
      for (int ni = 0; ni < 4; ni++) {
        int col = n0 + ni * 16 + l16;        // 0..1023 (Q|K)
        float bval = bias[col & 511];
#pragma unroll
        for (int r = 0; r < 4; r++) {
          int row = m0 + mi * 16 + quad * 4 + r;
          C[(size_t)row * 1024 + col] = f2bf((acc[mi][ni][r] + bval) * smul);
        }
      }
  } else {
    // V -> vT[(b*8+h)*64 + d][chunk*128 + slot]; slot = mi*32+quad*8+half*4+r
    int b = my >> 3;
    int chunk = my & 7;
    int half = mw >> 6;                      // 0 or 1
#pragma unroll
    for (int mi = 0; mi < 4; mi++)
#pragma unroll
      for (int ni = 0; ni < 4; ni++) {
        int c = (n0 - 1024) + ni * 16 + l16; // 0..511 v-col
        int h = c >> 6, d = c & 63;
        float bval = bias[c];
        short4v pk;
#pragma unroll
        for (int r = 0; r < 4; r++) pk[r] = f2bf(acc[mi][ni][r] + bval);
        short* dst = vT + ((size_t)((b * 8 + h) * 64 + d)) * 1024
                        + chunk * 128 + mi * 32 + quad * 8 + half * 4;
        *(short4v*)dst = pk;
      }
  }
}

// ---------------- stage 6: GEMM + bias + residual (fp32 out; r10-proven) ----
__global__ __launch_bounds__(256) void gemm_out(const short* __restrict__ A,
                                                const short* __restrict__ Bt,
                                                const float* __restrict__ bias,
                                                const float* __restrict__ xres,
                                                float* __restrict__ out) {
  __shared__ __align__(16) short As[2][128 * 32];
  __shared__ __align__(16) short Bs[2][128 * 32];
  int tid = threadIdx.x;
  int w = tid >> 6, lane = tid & 63;
  int quad = lane >> 4, l16 = lane & 15;
  int mw = (w >> 1) * 64, nw = (w & 1) * 64;
  int lin = blockIdx.y * 4 + blockIdx.x;    // linear dispatch id (x fastest)
  int my = (lin & 7) + ((lin / 32) << 3);   // M-tile 0..127 (XCD-chunked)
  int mx = (lin >> 3) & 3;                  // N-tile 0..3
  const short* Atile = A + (size_t)(my * 128) * 512;
  const short* Btile = Bt + (size_t)(mx * 128) * 512;
  int srow = (w << 4) + (lane >> 2);
  int scol = (lane & 3) * 8;
  f32x4 acc[4][4] = {};
  for (int k0 = 0; k0 < 512; k0 += 64) {
    __syncthreads();
    gload_lds16(&Atile[(size_t)srow * 512 + k0 + scol],             &As[0][w * 512]);
    gload_lds16(&Atile[(size_t)(srow + 64) * 512 + k0 + scol],      &As[0][2048 + w * 512]);
    gload_lds16(&Atile[(size_t)srow * 512 + k0 + 32 + scol],        &As[1][w * 512]);
    gload_lds16(&Atile[(size_t)(srow + 64) * 512 + k0 + 32 + scol], &As[1][2048 + w * 512]);
    gload_lds16(&Btile[(size_t)srow * 512 + k0 + scol],             &Bs[0][w * 512]);
    gload_lds16(&Btile[(size_t)(srow + 64) * 512 + k0 + scol],      &Bs[0][2048 + w * 512]);
    gload_lds16(&Btile[(size_t)srow * 512 + k0 + 32 + scol],        &Bs[1][w * 512]);
    gload_lds16(&Btile[(size_t)(srow + 64) * 512 + k0 + 32 + scol], &Bs[1][2048 + w * 512]);
    __syncthreads();
    short8 af[2][4], bf[2][4];
#pragma unroll
    for (int s = 0; s < 2; s++)
#pragma unroll
      for (int i = 0; i < 4; i++) {
        af[s][i] = *(const short8*)(&As[s][(mw + i * 16 + l16) * 32 + quad * 8]);
        bf[s][i] = *(const short8*)(&Bs[s][(nw + i * 16 + l16) * 32 + quad * 8]);
      }
#pragma unroll
    for (int mi = 0; mi < 4; mi++)
#pragma unroll
      for (int ni = 0; ni < 4; ni++) {
        acc[mi][ni] = __builtin_amdgcn_mfma_f32_16x16x32_bf16(af[0][mi], bf[0][ni], acc[mi][ni], 0, 0, 0);
        acc[mi][ni] = __builtin_amdgcn_mfma_f32_16x16x32_bf16(af[1][mi], bf[1][ni], acc[mi][ni], 0, 0, 0);
      }
  }
  int m0 = my * 128 + mw;
  int n0 = mx * 128 + nw;
#pragma unroll
  for (int mi = 0; mi < 4; mi++)
#pragma unroll
    for (int ni = 0; ni < 4; ni++) {
      int col = n0 + ni * 16 + l16;
      float bval = bias[col];
#pragma unroll
      for (int r = 0; r < 4; r++) {
        int row = m0 + mi * 16 + quad * 4 + r;
        out[(size_t)row * 512 + col] = acc[mi][ni][r] + bval + xres[(size_t)row * 512 + col];
      }
    }
}

// ---------------- stage 5: attention — r10 dataflow + LDS trim to 32768 -----
// r13 (sole change): denomL eliminated — denominators live in Lbuf's row
// padding (columns 64..67 of the [q][68] layout were 4KB of holes). LDS
// 33792 -> 32768 exactly: 5 blocks/CU (5 x 32768 = 160KB), 20 waves/CU vs
// 16 before — +25% resident concurrency on a latency-bound kernel.
// Main loop / dataflow byte-identical to r10. New ordering requirement:
// one __syncthreads() after the main loop before the pad writes (Lbuf
// aliases the K buffers; old denomL lived outside them). Pad writes touch
// only cols 64..67; O^T accumulation touches only cols 0..63 — no overlap.
// (8-wave merged-qt remains ABANDONED: r4 NaN, r11 absmax 0.18.)
__global__ __launch_bounds__(256) void attn_kernel(const short* __restrict__ Q,
                                                   const short* __restrict__ Kmat,
                                                   const short* __restrict__ vTg,
                                                   short* __restrict__ O) {
  int tid = threadIdx.x;
  int w = tid >> 6, lane = tid & 63;
  int quad = lane >> 4, l16 = lane & 15;
  int lin = blockIdx.y * 128 + blockIdx.x;   // linear dispatch id (x fastest)
  int bh = (lin & 7) * 16 + (lin >> 7);      // XCD-chunked: xcd owns 16 bh
  int qt = (lin >> 3) & 15;                  // 16 same-bh blocks consecutive
  int b = bh >> 3, h = bh & 7;
  size_t base  = ((size_t)b * T_) * 1024 + (size_t)h * 64;
  size_t vbase = ((size_t)bh * 64) * 1024;
  size_t obase = ((size_t)b * T_) * 512 + (size_t)h * 64;
  int qrow0 = qt * 64;

  __shared__ __align__(16) char smem[32768];
  short* KTb[2];
  KTb[0] = (short*)smem;                    // K dbuf half 0: 128 keys x 64d, swizzled
  KTb[1] = (short*)(smem + 16384);          // K dbuf half 1
  float* Lbuf = (float*)smem;               // epilogue union [q][68]; cols 64-67 = denom pad

  // Q as B-frags: B[k=d=quad*8+j][n=q=l16], 4 q-tiles x 2 d-halves
  short8 qf0[4], qf1[4];
#pragma unroll
  for (int g = 0; g < 4; g++) {
    const short* qp = Q + base + (size_t)(qrow0 + g * 16 + l16) * 1024 + quad * 8;
    qf0[g] = *(const short8*)qp;
    qf1[g] = *(const short8*)(qp + 32);
  }

  // K staging descriptors: lane's 16B block index bk = w*256 + n*64 + lane,
  // bank swizzle applied on the GLOBAL address side (LDS dst stays linear).
  const short* ksrc[4];
#pragma unroll
  for (int n = 0; n < 4; n++) {
    int bk = w * 256 + n * 64 + lane;
    int key = bk >> 3, jc = bk & 7;
    int dcol = jc ^ (key & 7);
    ksrc[n] = Kmat + base + (size_t)key * 1024 + dcol * 8;
  }

  // V fragment base: d-row = l16 (+f*16), key-slot = w*4+quad (vT layout)
  const short* vp0 = vTg + vbase + (size_t)l16 * 1024 + (w * 4 + quad) * 8;

  // K fragment LDS offsets (shorts), loop-invariant
  int l7 = l16 & 7;
  int kA0 = ((w * 16 + l16) * 8 + (quad ^ l7)) * 8;
  int kA1 = ((w * 16 + l16) * 8 + ((quad + 4) ^ l7)) * 8;
  int kB0 = kA0 + 4096;   // key + 64
  int kB1 = kA1 + 4096;

  f32x4 oacc[4][4] = {};   // O^T[d-tile f][q-tile g]
  float lsum[4] = {0.f, 0.f, 0.f, 0.f};

  // prologue: stage tile 0 into buffer 0
#pragma unroll
  for (int n = 0; n < 4; n++)
    gload_lds16(ksrc[n], KTb[0] + (w * 256 + n * 64) * 8);

#pragma unroll
  for (int t = 0; t < 8; t++) {
    short* KTc = KTb[t & 1];
    short* KTn = KTb[(t + 1) & 1];
    __syncthreads();   // drains vmcnt: K(t) staged; KTn's last readers done
    // V fragments for tile t: global->reg, issued first
    short8 vfr[4];
#pragma unroll
    for (int f = 0; f < 4; f++)
      vfr[f] = *(const short8*)(vp0 + (size_t)f * 16384 + t * 128);
    // stage K(t+1) into the other buffer — in flight across this whole phase
    if (t < 7) {
#pragma unroll
      for (int n = 0; n < 4; n++)
        gload_lds16(ksrc[n] + (size_t)(t + 1) * 131072, KTn + (w * 256 + n * 64) * 8);
    }
    // K fragments for tile t from LDS
    short8 ka0 = *(const short8*)(KTc + kA0);
    short8 ka1 = *(const short8*)(KTc + kA1);
    short8 kb0 = *(const short8*)(KTc + kB0);
    short8 kb1 = *(const short8*)(KTc + kB1);

#pragma unroll
    for (int g = 0; g < 4; g++) {
      f32x4 za = {}, zb = {};
      __builtin_amdgcn_s_setprio(1);
      za = __builtin_amdgcn_mfma_f32_16x16x32_bf16(ka0, qf0[g], za, 0, 0, 0);
      za = __builtin_amdgcn_mfma_f32_16x16x32_bf16(ka1, qf1[g], za, 0, 0, 0);
      zb = __builtin_amdgcn_mfma_f32_16x16x32_bf16(kb0, qf0[g], zb, 0, 0, 0);
      zb = __builtin_amdgcn_mfma_f32_16x16x32_bf16(kb1, qf1[g], zb, 0, 0, 0);
      __builtin_amdgcn_s_setprio(0);
      float pa0 = fexp2(za[0]), pa1 = fexp2(za[1]);
      float pa2 = fexp2(za[2]), pa3 = fexp2(za[3]);
      float pb0 = fexp2(zb[0]), pb1 = fexp2(zb[1]);
      float pb2 = fexp2(zb[2]), pb3 = fexp2(zb[3]);
      lsum[g] += (pa0 + pa1) + (pa2 + pa3) + ((pb0 + pb1) + (pb2 + pb3));
      short2 a01 = pack_bf2(pa0, pa1), a23 = pack_bf2(pa2, pa3);
      short2 b01 = pack_bf2(pb0, pb1), b23 = pack_bf2(pb2, pb3);
      short8 pf;
      pf[0] = a01.x; pf[1] = a01.y; pf[2] = a23.x; pf[3] = a23.y;
      pf[4] = b01.x; pf[5] = b01.y; pf[6] = b23.x; pf[7] = b23.y;
      __builtin_amdgcn_s_setprio(1);
#pragma unroll
      for (int f = 0; f < 4; f++)
        oacc[f][g] = __builtin_amdgcn_mfma_f32_16x16x32_bf16(vfr[f], pf, oacc[f][g], 0, 0, 0);
      __builtin_amdgcn_s_setprio(0);
    }
  }

  // per-lane lsum covers this wave's keys for query g*16+l16; sum over quads
#pragma unroll
  for (int g = 0; g < 4; g++) {
    lsum[g] += __shfl_xor(lsum[g], 16, 64);
    lsum[g] += __shfl_xor(lsum[g], 32, 64);
  }
  // all K-LDS reads are done; smem can be repurposed as Lbuf from here
  __syncthreads();
  // denominators into the row pad: Lbuf[q][64+w] (cols 64..67, untouched by
  // the O^T accumulation which writes cols 0..63 only)
  if (quad == 0) {
#pragma unroll
    for (int g = 0; g < 4; g++)
      Lbuf[(g * 16 + l16) * 68 + 64 + w] = lsum[g];
  }
  // sequential cross-wave accumulation of O^T into Lbuf (transposed to [q][d])
  for (int ww = 0; ww < 4; ww++) {
    __syncthreads();
    if (w == ww) {
#pragma unroll
      for (int g = 0; g < 4; g++)
#pragma unroll
        for (int f = 0; f < 4; f++) {
          float* p = &Lbuf[(g * 16 + l16) * 68 + f * 16 + quad * 4];
          if (ww == 0) *(f32x4*)p = oacc[f][g];
          else         *(f32x4*)p = *(f32x4*)p + oacc[f][g];
        }
    }
  }
  __syncthreads();

  // coalesced writeout: thread -> (q = tid/4, 16-wide d segment)
  int q = tid >> 2, seg = tid & 3;
  float4 dnv = *(const float4*)(&Lbuf[q * 68 + 64]);
  float dn = (dnv.x + dnv.y) + (dnv.z + dnv.w);
  float rinv = __frcp_rn(dn);
  const float* row = &Lbuf[q * 68 + seg * 16];
  short8 o0, o1;
#pragma unroll
  for (int i = 0; i < 8; i++) o0[i] = f2bf(row[i] * rinv);
#pragma unroll
  for (int i = 0; i < 8; i++) o1[i] = f2bf(row[8 + i] * rinv);
  short* op = O + obase + (size_t)(qrow0 + q) * 512 + seg * 16;
  *(short8*)op = o0;
  *(short8*)(op + 8) = o1;
}

extern "C" void kernel_launch(void* const* d_in, const int* in_sizes, int n_in,
                              void* d_out, int out_size, void* d_ws, size_t ws_size,
                              hipStream_t stream) {
  const float* x     = (const float*)d_in[0];
  const float* gamma = (const float*)d_in[1];
  const float* beta  = (const float*)d_in[2];
  const float* wq    = (const float*)d_in[3];
  const float* bq    = (const float*)d_in[4];
  const float* wk    = (const float*)d_in[5];
  const float* bk    = (const float*)d_in[6];
  const float* wv    = (const float*)d_in[7];
  const float* bv    = (const float*)d_in[8];
  const float* wo    = (const float*)d_in[9];
  const float* bo    = (const float*)d_in[10];
  float* out = (float*)d_out;

  char* ws = (char*)d_ws;
  const size_t XN_ELEMS = (size_t)B_ * T_ * C_;
  size_t off = 0;
  off += 256;                                              // (reserved)
  float2* partials = (float2*)(ws + off); off += 16 * 64 * sizeof(float2);
  short* xn    = (short*)(ws + off); off += XN_ELEMS * 2;
  short* wqkvT = (short*)(ws + off); off += (size_t)1536 * 512 * 2;
  short* woT   = (short*)(ws + off); off += (size_t)512 * 512 * 2;
  short* qkv   = (short*)(ws + off); off += (size_t)B_ * T_ * 1024 * 2;  // Q|K compact
  short* vTb   = (short*)(ws + off); off += XN_ELEMS * 2;
  short* ao    = (short*)(ws + off); off += XN_ELEMS * 2;

  stats1_trans_kernel<<<5120, 256, 0, stream>>>(x, partials, wq, wk, wv, wo, wqkvT, woT);
  norm_kernel<<<2048, 256, 0, stream>>>(x, gamma, beta, partials, xn);

  gemm_qkv<<<dim3(12, 128), 256, 0, stream>>>(xn, wqkvT, bq, bk, bv, qkv, vTb);

  attn_kernel<<<dim3(128, 16), 256, 0, stream>>>(qkv, qkv + 512, vTb, ao);

  gemm_out<<<dim3(4, 128), 256, 0, stream>>>(ao, woT, bo, x, out);
}